// Round 9
// baseline (115.174 us; speedup 1.0000x reference)
//
#include <hip/hip_runtime.h>
#include <hip/hip_bf16.h>

#define NRAYS 8192
#define SAMP  128
#define DVD   27
#define NFEAT 15

typedef float  f32x4  __attribute__((ext_vector_type(4)));
typedef short  short8 __attribute__((ext_vector_type(8)));
typedef unsigned int u32x2 __attribute__((ext_vector_type(2)));
typedef unsigned int u32x4 __attribute__((ext_vector_type(4)));

// ---- precomputed weight image in d_ws (shorts = bf16), SWIZZLED LDS LAYOUT --
//  W1t  @byte 0     [64 prow][128B]  swizzled; prow = (n&3)*16 + (n>>2)
//  Ct   @byte 8192  [64 prow][128B]  swizzled; C = W2[:,1:16] @ V1[0:15,:]
//  Sm   @byte 16384 [4][64]shorts : row0 = W2[:,0]; rows1..3 = V2 cols 0..2
//  gvc  @byte 16896 float[64] = c1 + b2[1:16] @ V1[0:15,:] ; gvc[64] = dtv
#define GVC_OFF  16896
#define IMG_CHUNKS 1056     // 16896 / 16

// swizzle: all row-major-128B-row LDS arrays use
//   byte(row, colbyte) = row*128 + (colbyte ^ ((row&7)<<4))
static __device__ __forceinline__ int XB(int row, int cb) {
    return row * 128 + (cb ^ ((row & 7) << 4));
}
// same in short units (for prep): short(row,k) = row*64 + (k ^ ((row&7)<<3))
static __device__ __forceinline__ int XS(int row, int k) {
    return row * 64 + (k ^ ((row & 7) << 3));
}

// fast fp32 -> bf16 (round-half-up)
static __device__ __forceinline__ void stbf(short* p, float x) {
    union { unsigned u; struct { short lo, hi; } s; } v;
    v.u = __float_as_uint(x) + 0x8000u;
    *p = v.s.hi;
}
static __device__ __forceinline__ float bf2f(short s) {
    return __uint_as_float(((unsigned)(unsigned short)s) << 16);
}
// pack two fp32 -> dword of two bf16 (lo -> low half), HW RNE convert
static __device__ __forceinline__ unsigned pk2bf(float lo, float hi) {
    unsigned r;
    asm("v_cvt_pk_bf16_f32 %0, %1, %2" : "=v"(r) : "v"(lo), "v"(hi));
    return r;
}
static __device__ __forceinline__ float sin_fast(float x) {
    float r = x * 0.15915494309189535f;
    r = r - floorf(r);
    return __builtin_amdgcn_sinf(r);
}
static __device__ __forceinline__ float cos_fast(float x) {
    float r = x * 0.15915494309189535f;
    r = r - floorf(r);
    return __builtin_amdgcn_cosf(r);
}
static __device__ __forceinline__ float sigm(float x) {
    return 1.0f / (1.0f + __expf(-x));
}

// E k-layout (shorts within a 64-short row):
//   bands 0..4 : k = 6*b + {sx,sy,sz,cx,cy,cz}   (dwords 0..14, half0)
//   px,py      : k = 30,31                        (dword 15, half0)
//   bands 5..9 : k = 32 + 6*(b-5) + {...}         (dwords 16..30, half1)
//   pz, 1.0    : k = 62,63                        (dword 31, half1; bias col)
static __device__ __forceinline__ int kmap(int r) {
    if (r == 0) return 30;
    if (r == 1) return 31;
    if (r == 2) return 62;
    const int q = r - 3, i = q / 6, c = q - 6 * i;
    return (i < 5 ? 6 * i : 32 + 6 * (i - 5)) + c;
}

// positional-encoding VALU block (pipelined across qq: computed one iter ahead)
static __device__ __forceinline__ void enc_compute(
    int s, float t0v, float trange,
    float ox, float oy, float oz, float dx, float dy, float dz,
    float fmul, int half, unsigned* e) {
    const float t = t0v + (float)s * (1.0f / 127.0f) * trange;
    const float px = ox + dx * t, py = oy + dy * t, pz = oz + dz * t;
    float rx = px * fmul; rx -= floorf(rx);
    float ry = py * fmul; ry -= floorf(ry);
    float rz = pz * fmul; rz -= floorf(rz);
    float sx = __builtin_amdgcn_sinf(rx), cx = __builtin_amdgcn_cosf(rx);
    float sy = __builtin_amdgcn_sinf(ry), cy = __builtin_amdgcn_cosf(ry);
    float sz = __builtin_amdgcn_sinf(rz), cz = __builtin_amdgcn_cosf(rz);
    #pragma unroll
    for (int j = 0; j < 5; j++) {
        e[3 * j + 0] = pk2bf(sx, sy);
        e[3 * j + 1] = pk2bf(sz, cx);
        e[3 * j + 2] = pk2bf(cy, cz);
        if (j < 4) {   // double-angle: s'=2sc, c'=1-2s^2
            const float tx = sx + sx, ty = sy + sy, tz = sz + sz;
            const float nsx = tx * cx, nsy = ty * cy, nsz = tz * cz;
            cx = __builtin_fmaf(-tx, sx, 1.0f);
            cy = __builtin_fmaf(-ty, sy, 1.0f);
            cz = __builtin_fmaf(-tz, sz, 1.0f);
            sx = nsx; sy = nsy; sz = nsz;
        }
    }
    e[15] = half ? pk2bf(pz, 1.0f) : pk2bf(px, py);
}

// ---------------- prep kernel: build weight image + dtv once ----------------
__global__ void __launch_bounds__(256)
prep_kernel(const float* __restrict__ W1, const float* __restrict__ b1,
            const float* __restrict__ W2, const float* __restrict__ b2,
            const float* __restrict__ V1, const float* __restrict__ c1,
            const float* __restrict__ V2, const float* __restrict__ tmin,
            const float* __restrict__ tmax, short* __restrict__ img,
            float* __restrict__ gvc) {
    if (blockIdx.x == 34) {   // dt reduce: dtv = mean(tmax - tmin) / SAMP
        __shared__ float red[4];
        const int tid = threadIdx.x, lane = tid & 63, wave = tid >> 6;
        const float4* tm0 = (const float4*)tmin;
        const float4* tm1 = (const float4*)tmax;
        float s = 0.0f;
        #pragma unroll
        for (int it = 0; it < 8; it++) {
            const int i = tid + it * 256;
            const float4 a = tm1[i], b = tm0[i];
            s += (a.x - b.x) + (a.y - b.y) + (a.z - b.z) + (a.w - b.w);
        }
        #pragma unroll
        for (int off = 32; off > 0; off >>= 1)
            s += __shfl_xor(s, off, 64);
        if (lane == 0) red[wave] = s;
        __syncthreads();
        if (tid == 0)
            gvc[64] = (red[0] + red[1] + red[2] + red[3]) *
                      (1.0f / ((float)NRAYS * (float)SAMP));
        return;
    }
    const int g = blockIdx.x * 256 + threadIdx.x;   // 0..8703, blocks 0..33
    if (g < 4032) {                       // W1 [63][64] row-major -> swizzled
        const int r = g >> 6, n = g & 63;
        const int prow = (n & 3) * 16 + (n >> 2);
        stbf(&img[XS(prow, kmap(r))], W1[g]);
    } else if (g < 4096) {                // bias column k=63 = b1
        const int n = g - 4032;
        const int prow = (n & 3) * 16 + (n >> 2);
        stbf(&img[XS(prow, 63)], b1[n]);
    } else if (g < 8192) {                // C[k][n] = sum_j W2[k][1+j]*V1[j][n]
        const int i = g - 4096;
        const int k = i >> 6, n = i & 63;
        const int prow = (n & 3) * 16 + (n >> 2);
        float a = 0.0f;
        #pragma unroll
        for (int j = 0; j < 15; j++) a += W2[k * 16 + 1 + j] * V1[j * 64 + n];
        stbf(&img[4096 + XS(prow, k)], a);
    } else if (g < 8256) {                // Sm row0 = sigma weight col
        const int k = g - 8192;
        stbf(&img[8192 + k], W2[k * 16]);
    } else if (g < 8448) {                // Sm rows1..3 = V2 cols
        const int i = g - 8256, c = i >> 6, k = i & 63;
        stbf(&img[8192 + 64 + c * 64 + k], V2[k * 3 + c]);
    } else if (g < 8512) {                // gvc
        const int n = g - 8448;
        float a = c1[n];
        #pragma unroll
        for (int j = 0; j < 15; j++) a += b2[1 + j] * V1[j * 64 + n];
        gvc[n] = a;
    }
}

// LDS layout (38400 B -> 4 blocks/CU, matching the 4-waves/SIMD register cap):
//   sE   @0     [4 waves][32 rows][128B] swizzled
//        (overlay pre-barrier2: sVde @0 [4][28]f)
//   sW1t @16384 [64 prow][128B] swizzled (persistent, fragments re-read per qq)
//   sCt  @24576 [64 prow][128B] swizzled (persistent)
//   sSm  @32768 [4][64]s, sOm @33280 [4][128]f, sRgb @35328 [4][384]s
// NOTE: sOm holds RAW -sigma*dt (exp deferred); sRgb holds RAW pre-sigmoid val.
#define SMEM_BYTES 38400

// (256,4): 4 waves/SIMD needs <=128 unified V+A regs; feasible (R4/R7-proven).
__global__ void __launch_bounds__(256, 4)
march_kernel(const float* __restrict__ orig,
             const float* __restrict__ dirs,
             const float* __restrict__ tmin,
             const float* __restrict__ tmax,
             const float* __restrict__ b2,
             const float* __restrict__ c2,
             const float* __restrict__ V1,
             const short* __restrict__ img,
             const float* __restrict__ gvc,
             float* __restrict__ out) {
    __shared__ __align__(16) char smem[SMEM_BYTES];
    char*  const sEc   = smem;                     // working E tiles
    char*  const sW1tc = smem + 16384;             // persistent
    char*  const sCtc  = smem + 24576;             // persistent
    short* const sSm   = (short*)(smem + 32768);
    float* const sOm   = (float*)(smem + 33280);
    short* const sRgb  = (short*)(smem + 35328);
    float* const sVde  = (float*)(smem);           // overlay, dead at barrier 2

    const int tid  = threadIdx.x;
    const int lane = tid & 63;
    const int wave = tid >> 6;
    const int ray  = blockIdx.x * 4 + wave;

    // ---- weight staging: copy prebuilt image -> persistent region @16384 ----
    {
        const u32x4* src = (const u32x4*)img;
        u32x4* dst = (u32x4*)(smem + 16384);
        #pragma unroll
        for (int it = 0; it < 5; it++) {
            const int i = tid + it * 256;
            if (i < IMG_CHUNKS) dst[i] = src[i];
        }
    }

    // ---- per-ray scalars ----
    const float ox = orig[ray * 3 + 0];
    const float oy = orig[ray * 3 + 1];
    const float oz = orig[ray * 3 + 2];
    const float dx = dirs[ray * 3 + 0];
    const float dy = dirs[ray * 3 + 1];
    const float dz = dirs[ray * 3 + 2];
    const float t0v = tmin[ray];
    const float trange = tmax[ray] - t0v;
    const float negdtv = -gvc[64];   // dtv precomputed by prep

    // ---- view-dir encoding (fp32) -> sVde (per-wave) ----
    {
        const float nrm = sqrtf(dx * dx + dy * dy + dz * dz);
        const float inv = 1.0f / (nrm + 1e-8f);
        const float vx = dx * inv, vy = dy * inv, vz = dz * inv;
        if (lane < DVD) {
            float val;
            if (lane < 3) {
                val = (lane == 0) ? vx : ((lane == 1) ? vy : vz);
            } else {
                const int q = lane - 3;
                const int b = q / 6;
                const int r = q - 6 * b;
                const bool isSin = (r < 3);
                const int d = isSin ? r : (r - 3);
                const float comp = (d == 0) ? vx : ((d == 1) ? vy : vz);
                const float a = (float)(1 << b) * comp;
                val = isSin ? sin_fast(a) : cos_fast(a);
            }
            sVde[wave * 28 + lane] = val;
        }
    }
    __syncthreads();   // barrier 1: staging copy + vde writes complete

    const int nfr  = lane & 15;   // n (or m) within a 16-tile
    const int quad = lane >> 4;
    const int cbq  = quad * 16;   // byte col of this lane's k-fragment

    // ---- gv[nt] = gvc[n] + sum_q vde[q] * V1[15+q][n],  n = 4*nfr+nt ----
    float gv[4];
    {
        const f32x4 g0 = *(const f32x4*)&gvc[4 * nfr];
        gv[0] = g0.x; gv[1] = g0.y; gv[2] = g0.z; gv[3] = g0.w;
    }
    #pragma unroll 9
    for (int q = 0; q < DVD; q++) {
        const float e = sVde[wave * 28 + q];
        const f32x4 vv = *(const f32x4*)&V1[(NFEAT + q) * 64 + 4 * nfr];
        gv[0] += e * vv.x; gv[1] += e * vv.y;
        gv[2] += e * vv.z; gv[3] += e * vv.w;
    }

    const float bb2 = b2[0];
    const float bc2 = (nfr < 3) ? c2[nfr] : 0.0f;

    __syncthreads();   // barrier 2: sVde reads done before sE overwrite

    char* const myE = sEc + wave * 4096;   // 32 rows x 128B, swizzled

    const int sl   = lane >> 1;   // local sample 0..31 (enc phase)
    const int half = lane & 1;
    // chain seed frequency: half0 starts at band 0 (f=1), half1 at band 5 (f=32)
    const float fmul = half ? 5.0929581789406507f      // 32 / (2*pi)
                            : 0.15915494309189535f;    //  1 / (2*pi)

    // software pipeline: e[] always holds the encoding for the CURRENT qq,
    // computed during the PREVIOUS iteration's MFMA phases (prologue for qq=0)
    unsigned e[16] __attribute__((aligned(16)));
    enc_compute(sl, t0v, trange, ox, oy, oz, dx, dy, dz, fmul, half, e);

    #pragma unroll 1
    for (int qq = 0; qq < 4; qq++) {
        // --- write pre-computed encodings: 4x ds_write_b128 (swizzled) ---
        #pragma unroll
        for (int w = 0; w < 4; w++)
            *(u32x4*)(myE + XB(sl, half * 64 + w * 16)) =
                *(const u32x4*)&e[4 * w];
        // --- layer 1: h = relu(E @ W1 + b1), nt-split (acc1 peak 16 AGPR) ---
        {
            short8 af[2][2];
            #pragma unroll
            for (int mt = 0; mt < 2; mt++)
                #pragma unroll
                for (int kt = 0; kt < 2; kt++)
                    af[mt][kt] = *(const short8*)(myE + XB(nfr + 16 * mt, cbq + kt * 64));
            #pragma unroll
            for (int nth = 0; nth < 2; nth++) {
                f32x4 acc1[2][2];
                __builtin_amdgcn_s_setprio(1);
                #pragma unroll
                for (int j = 0; j < 2; j++) {
                    const int nt = 2 * nth + j;
                    const short8 wf0 = *(const short8*)
                        (sW1tc + XB(nt * 16 + nfr, cbq));
                    #pragma unroll
                    for (int mt = 0; mt < 2; mt++)
                        acc1[mt][j] = __builtin_amdgcn_mfma_f32_16x16x32_bf16(
                            af[mt][0], wf0, (f32x4){0.0f, 0.0f, 0.0f, 0.0f}, 0, 0, 0);
                    const short8 wf1 = *(const short8*)
                        (sW1tc + XB(nt * 16 + nfr, cbq + 64));
                    #pragma unroll
                    for (int mt = 0; mt < 2; mt++)
                        acc1[mt][j] = __builtin_amdgcn_mfma_f32_16x16x32_bf16(
                            af[mt][1], wf1, acc1[mt][j], 0, 0, 0);
                }
                __builtin_amdgcn_s_setprio(0);
                #pragma unroll
                for (int mt = 0; mt < 2; mt++)
                    #pragma unroll
                    for (int r = 0; r < 4; r++) {
                        const int m = 4 * quad + r + 16 * mt;
                        *(unsigned*)(myE + XB(m, 8 * nfr + 4 * nth)) =
                            pk2bf(fmaxf(acc1[mt][0][r], 0.0f),
                                  fmaxf(acc1[mt][1][r], 0.0f));
                    }
            }
        }
        // --- A-fragments of h (shared by sigma and C GEMMs) ---
        short8 ah[2][2];
        #pragma unroll
        for (int mt = 0; mt < 2; mt++)
            #pragma unroll
            for (int kt = 0; kt < 2; kt++)
                ah[mt][kt] = *(const short8*)(myE + XB(nfr + 16 * mt, cbq + kt * 64));
        // --- sigma: acc2 = b2[0] + h @ w2s (B broadcast from Sm row 0);
        //     store RAW -sigma*dt, exp deferred to the final phase ---
        {
            f32x4 acc2[2];
            acc2[0] = (f32x4){bb2, bb2, bb2, bb2};
            acc2[1] = (f32x4){bb2, bb2, bb2, bb2};
            short8 w2sf[2];
            #pragma unroll
            for (int kt = 0; kt < 2; kt++)
                w2sf[kt] = *(const short8*)&sSm[quad * 8 + kt * 32];
            __builtin_amdgcn_s_setprio(1);
            #pragma unroll
            for (int mt = 0; mt < 2; mt++)
                #pragma unroll
                for (int kt = 0; kt < 2; kt++)
                    acc2[mt] = __builtin_amdgcn_mfma_f32_16x16x32_bf16(
                        ah[mt][kt], w2sf[kt], acc2[mt], 0, 0, 0);
            __builtin_amdgcn_s_setprio(0);
            if (nfr == 0) {
                #pragma unroll
                for (int mt = 0; mt < 2; mt++)
                    #pragma unroll
                    for (int r = 0; r < 4; r++) {
                        const int m = 4 * quad + r + 16 * mt;
                        sOm[wave * 128 + qq * 32 + m] =
                            fmaxf(acc2[mt][r], 0.0f) * negdtv;
                    }
            }
        }
        // --- g = relu(h @ C + gv), nt-split; Ct prow = (2nth+j)*16 + nfr ---
        #pragma unroll
        for (int nth = 0; nth < 2; nth++) {
            f32x4 acc3[2][2];
            #pragma unroll
            for (int mt = 0; mt < 2; mt++)
                #pragma unroll
                for (int j = 0; j < 2; j++) {
                    const float gvi = gv[2 * nth + j];
                    acc3[mt][j] = (f32x4){gvi, gvi, gvi, gvi};
                }
            __builtin_amdgcn_s_setprio(1);
            #pragma unroll
            for (int j = 0; j < 2; j++)
                #pragma unroll
                for (int kt = 0; kt < 2; kt++) {
                    const short8 cf = *(const short8*)
                        (sCtc + XB((2 * nth + j) * 16 + nfr, cbq + kt * 64));
                    #pragma unroll
                    for (int mt = 0; mt < 2; mt++)
                        acc3[mt][j] = __builtin_amdgcn_mfma_f32_16x16x32_bf16(
                            ah[mt][kt], cf, acc3[mt][j], 0, 0, 0);
                }
            __builtin_amdgcn_s_setprio(0);
            #pragma unroll
            for (int mt = 0; mt < 2; mt++)
                #pragma unroll
                for (int r = 0; r < 4; r++) {
                    const int m = 4 * quad + r + 16 * mt;
                    *(unsigned*)(myE + XB(m, 8 * nfr + 4 * nth)) =
                        pk2bf(fmaxf(acc3[mt][0][r], 0.0f),
                              fmaxf(acc3[mt][1][r], 0.0f));
                }
        }
        // --- pipelined: compute NEXT iteration's encodings (independent VALU;
        //     scheduler fills V2/C stall slots with it). qq=3 result unused. ---
        enc_compute((qq + 1) * 32 + sl, t0v, trange, ox, oy, oz, dx, dy, dz,
                    fmul, half, e);
        // --- V2: rgb_pre = g @ V2 + c2; store RAW bf16, sigmoid deferred ---
        {
            f32x4 acc4[2];
            acc4[0] = (f32x4){bc2, bc2, bc2, bc2};
            acc4[1] = (f32x4){bc2, bc2, bc2, bc2};
            short8 agg[2][2];
            #pragma unroll
            for (int mt = 0; mt < 2; mt++)
                #pragma unroll
                for (int kt = 0; kt < 2; kt++)
                    agg[mt][kt] = *(const short8*)(myE + XB(nfr + 16 * mt, cbq + kt * 64));
            const int vr = 1 + ((nfr < 3) ? nfr : 2);
            short8 v2f[2];
            #pragma unroll
            for (int kt = 0; kt < 2; kt++)
                v2f[kt] = *(const short8*)&sSm[vr * 64 + quad * 8 + kt * 32];
            __builtin_amdgcn_s_setprio(1);
            #pragma unroll
            for (int mt = 0; mt < 2; mt++)
                #pragma unroll
                for (int kt = 0; kt < 2; kt++)
                    acc4[mt] = __builtin_amdgcn_mfma_f32_16x16x32_bf16(
                        agg[mt][kt], v2f[kt], acc4[mt], 0, 0, 0);
            __builtin_amdgcn_s_setprio(0);
            if (nfr < 3) {
                #pragma unroll
                for (int mt = 0; mt < 2; mt++)
                    #pragma unroll
                    for (int r = 0; r < 4; r++) {
                        const int m = 4 * quad + r + 16 * mt;
                        stbf(&sRgb[wave * 384 + (qq * 32 + m) * 3 + nfr],
                             acc4[mt][r]);
                    }
            }
        }
    }

    // ---- final: deferred exp/sigmoid + scan + weighted reduce (per wave) ----
    const float om0 = __expf(sOm[wave * 128 + 2 * lane]);
    const float om1 = __expf(sOm[wave * 128 + 2 * lane + 1]);
    const float al0 = 1.0f - om0;
    const float al1 = 1.0f - om1;

    float inc = om0 * om1;
    #pragma unroll
    for (int off = 1; off < 64; off <<= 1) {
        const float q = __shfl_up(inc, off, 64);
        if (lane >= off) inc *= q;
    }
    float Texc = __shfl_up(inc, 1, 64);
    if (lane == 0) Texc = 1.0f;

    const float T0 = Texc;
    const float T1 = Texc * om0;
    const float a0 = (T0 > 1e-4f) ? 1.0f : 0.0f;
    const float a1 = (T1 > 1e-4f) ? 1.0f : 0.0f;
    const float w0 = T0 * al0 * a0;
    const float w1 = T1 * al1 * a1;

    float cr = w0 * sigm(bf2f(sRgb[wave * 384 + (2 * lane) * 3 + 0])) +
               w1 * sigm(bf2f(sRgb[wave * 384 + (2 * lane + 1) * 3 + 0]));
    float cg = w0 * sigm(bf2f(sRgb[wave * 384 + (2 * lane) * 3 + 1])) +
               w1 * sigm(bf2f(sRgb[wave * 384 + (2 * lane + 1) * 3 + 1]));
    float cb = w0 * sigm(bf2f(sRgb[wave * 384 + (2 * lane) * 3 + 2])) +
               w1 * sigm(bf2f(sRgb[wave * 384 + (2 * lane + 1) * 3 + 2]));
    float tp = (a0 > 0.0f ? om0 : 1.0f) * (a1 > 0.0f ? om1 : 1.0f);

    #pragma unroll
    for (int off = 32; off > 0; off >>= 1) {
        cr += __shfl_xor(cr, off, 64);
        cg += __shfl_xor(cg, off, 64);
        cb += __shfl_xor(cb, off, 64);
        tp *= __shfl_xor(tp, off, 64);
    }

    if (lane == 0) {
        out[ray * 3 + 0] = cr;
        out[ray * 3 + 1] = cg;
        out[ray * 3 + 2] = cb;
        out[NRAYS * 3 + ray] = tp;
    }
}

extern "C" void kernel_launch(void* const* d_in, const int* in_sizes, int n_in,
                              void* d_out, int out_size, void* d_ws, size_t ws_size,
                              hipStream_t stream) {
    const float* orig = (const float*)d_in[0];
    const float* dirs = (const float*)d_in[1];
    const float* tmin = (const float*)d_in[2];
    const float* tmax = (const float*)d_in[3];
    const float* W1   = (const float*)d_in[4];
    const float* b1   = (const float*)d_in[5];
    const float* W2   = (const float*)d_in[6];
    const float* b2   = (const float*)d_in[7];
    const float* V1   = (const float*)d_in[8];
    const float* c1   = (const float*)d_in[9];
    const float* V2   = (const float*)d_in[10];
    const float* c2   = (const float*)d_in[11];

    short* img = (short*)d_ws;
    float* gvc = (float*)((char*)d_ws + GVC_OFF);

    prep_kernel<<<35, 256, 0, stream>>>(W1, b1, W2, b2, V1, c1, V2,
                                        tmin, tmax, img, gvc);
    march_kernel<<<NRAYS / 4, 256, 0, stream>>>(orig, dirs, tmin, tmax,
                                                b2, c2, V1, img, gvc,
                                                (float*)d_out);
}

// Round 10
// 114.331 us; speedup vs baseline: 1.0074x; 1.0074x over previous
//
#include <hip/hip_runtime.h>
#include <hip/hip_bf16.h>

#define NRAYS 8192
#define SAMP  128
#define DVD   27
#define NFEAT 15

typedef float  f32x4  __attribute__((ext_vector_type(4)));
typedef short  short8 __attribute__((ext_vector_type(8)));
typedef unsigned int u32x2 __attribute__((ext_vector_type(2)));
typedef unsigned int u32x4 __attribute__((ext_vector_type(4)));

// ---- precomputed weight image in d_ws (shorts = bf16), SWIZZLED LDS LAYOUT --
//  W1t  @byte 0     [64 prow][128B]  swizzled; prow = (n&3)*16 + (n>>2)
//  Ct   @byte 8192  [64 prow][128B]  swizzled; C = W2[:,1:16] @ V1[0:15,:]
//  Sm   @byte 16384 [4][64]shorts : row0 = W2[:,0]; rows1..3 = V2 cols 0..2
//  gvc  @byte 16896 float[64] = c1 + b2[1:16] @ V1[0:15,:] ; gvc[64] = dtv
#define GVC_OFF  16896
#define IMG_CHUNKS 1056     // 16896 / 16

// swizzle: all row-major-128B-row LDS arrays use
//   byte(row, colbyte) = row*128 + (colbyte ^ ((row&7)<<4))
static __device__ __forceinline__ int XB(int row, int cb) {
    return row * 128 + (cb ^ ((row & 7) << 4));
}
// same in short units (for prep): short(row,k) = row*64 + (k ^ ((row&7)<<3))
static __device__ __forceinline__ int XS(int row, int k) {
    return row * 64 + (k ^ ((row & 7) << 3));
}

// fast fp32 -> bf16 (round-half-up)
static __device__ __forceinline__ void stbf(short* p, float x) {
    union { unsigned u; struct { short lo, hi; } s; } v;
    v.u = __float_as_uint(x) + 0x8000u;
    *p = v.s.hi;
}
static __device__ __forceinline__ float bf2f(short s) {
    return __uint_as_float(((unsigned)(unsigned short)s) << 16);
}
// pack two fp32 -> dword of two bf16 (lo -> low half), HW RNE convert
static __device__ __forceinline__ unsigned pk2bf(float lo, float hi) {
    unsigned r;
    asm("v_cvt_pk_bf16_f32 %0, %1, %2" : "=v"(r) : "v"(lo), "v"(hi));
    return r;
}
static __device__ __forceinline__ float sin_fast(float x) {
    float r = x * 0.15915494309189535f;
    r = r - floorf(r);
    return __builtin_amdgcn_sinf(r);
}
static __device__ __forceinline__ float cos_fast(float x) {
    float r = x * 0.15915494309189535f;
    r = r - floorf(r);
    return __builtin_amdgcn_cosf(r);
}
static __device__ __forceinline__ float sigm(float x) {
    return 1.0f / (1.0f + __expf(-x));
}

// E k-layout (shorts within a 64-short row):
//   bands 0..4 : k = 6*b + {sx,sy,sz,cx,cy,cz}   (dwords 0..14, half0)
//   px,py      : k = 30,31                        (dword 15, half0)
//   bands 5..9 : k = 32 + 6*(b-5) + {...}         (dwords 16..30, half1)
//   pz, 1.0    : k = 62,63                        (dword 31, half1; bias col)
static __device__ __forceinline__ int kmap(int r) {
    if (r == 0) return 30;
    if (r == 1) return 31;
    if (r == 2) return 62;
    const int q = r - 3, i = q / 6, c = q - 6 * i;
    return (i < 5 ? 6 * i : 32 + 6 * (i - 5)) + c;
}

// ---------------- prep kernel: build weight image + dtv once ----------------
__global__ void __launch_bounds__(256)
prep_kernel(const float* __restrict__ W1, const float* __restrict__ b1,
            const float* __restrict__ W2, const float* __restrict__ b2,
            const float* __restrict__ V1, const float* __restrict__ c1,
            const float* __restrict__ V2, const float* __restrict__ tmin,
            const float* __restrict__ tmax, short* __restrict__ img,
            float* __restrict__ gvc) {
    if (blockIdx.x == 34) {   // dt reduce: dtv = mean(tmax - tmin) / SAMP
        __shared__ float red[4];
        const int tid = threadIdx.x, lane = tid & 63, wave = tid >> 6;
        const float4* tm0 = (const float4*)tmin;
        const float4* tm1 = (const float4*)tmax;
        float s = 0.0f;
        #pragma unroll
        for (int it = 0; it < 8; it++) {
            const int i = tid + it * 256;
            const float4 a = tm1[i], b = tm0[i];
            s += (a.x - b.x) + (a.y - b.y) + (a.z - b.z) + (a.w - b.w);
        }
        #pragma unroll
        for (int off = 32; off > 0; off >>= 1)
            s += __shfl_xor(s, off, 64);
        if (lane == 0) red[wave] = s;
        __syncthreads();
        if (tid == 0)
            gvc[64] = (red[0] + red[1] + red[2] + red[3]) *
                      (1.0f / ((float)NRAYS * (float)SAMP));
        return;
    }
    const int g = blockIdx.x * 256 + threadIdx.x;   // 0..8703, blocks 0..33
    if (g < 4032) {                       // W1 [63][64] row-major -> swizzled
        const int r = g >> 6, n = g & 63;
        const int prow = (n & 3) * 16 + (n >> 2);
        stbf(&img[XS(prow, kmap(r))], W1[g]);
    } else if (g < 4096) {                // bias column k=63 = b1
        const int n = g - 4032;
        const int prow = (n & 3) * 16 + (n >> 2);
        stbf(&img[XS(prow, 63)], b1[n]);
    } else if (g < 8192) {                // C[k][n] = sum_j W2[k][1+j]*V1[j][n]
        const int i = g - 4096;
        const int k = i >> 6, n = i & 63;
        const int prow = (n & 3) * 16 + (n >> 2);
        float a = 0.0f;
        #pragma unroll
        for (int j = 0; j < 15; j++) a += W2[k * 16 + 1 + j] * V1[j * 64 + n];
        stbf(&img[4096 + XS(prow, k)], a);
    } else if (g < 8256) {                // Sm row0 = sigma weight col
        const int k = g - 8192;
        stbf(&img[8192 + k], W2[k * 16]);
    } else if (g < 8448) {                // Sm rows1..3 = V2 cols
        const int i = g - 8256, c = i >> 6, k = i & 63;
        stbf(&img[8192 + 64 + c * 64 + k], V2[k * 3 + c]);
    } else if (g < 8512) {                // gvc
        const int n = g - 8448;
        float a = c1[n];
        #pragma unroll
        for (int j = 0; j < 15; j++) a += b2[1 + j] * V1[j * 64 + n];
        gvc[n] = a;
    }
}

// LDS layout (38400 B -> 4 blocks/CU, matching the 4-waves/SIMD register cap):
//   sE   @0     [4 waves][32 rows][128B] swizzled
//        (overlay pre-barrier2: sVde @0 [4][28]f)
//   sW1t @16384 [64 prow][128B] swizzled (persistent, fragments re-read per qq)
//   sCt  @24576 [64 prow][128B] swizzled (persistent)
//   sSm  @32768 [4][64]s, sOm @33280 [4][128]f, sRgb @35328 [4][384]s
// NOTE: sOm holds RAW -sigma*dt (exp deferred); sRgb holds RAW pre-sigmoid val.
#define SMEM_BYTES 38400

// (256,4): 4 waves/SIMD needs <=128 unified V+A regs; feasible (R4/R7-proven).
__global__ void __launch_bounds__(256, 4)
march_kernel(const float* __restrict__ orig,
             const float* __restrict__ dirs,
             const float* __restrict__ tmin,
             const float* __restrict__ tmax,
             const float* __restrict__ b2,
             const float* __restrict__ c2,
             const float* __restrict__ V1,
             const short* __restrict__ img,
             const float* __restrict__ gvc,
             float* __restrict__ out) {
    __shared__ __align__(16) char smem[SMEM_BYTES];
    char*  const sEc   = smem;                     // working E tiles
    char*  const sW1tc = smem + 16384;             // persistent
    char*  const sCtc  = smem + 24576;             // persistent
    short* const sSm   = (short*)(smem + 32768);
    float* const sOm   = (float*)(smem + 33280);
    short* const sRgb  = (short*)(smem + 35328);
    float* const sVde  = (float*)(smem);           // overlay, dead at barrier 2

    const int tid  = threadIdx.x;
    const int lane = tid & 63;
    const int wave = tid >> 6;
    const int ray  = blockIdx.x * 4 + wave;

    // ---- weight staging: copy prebuilt image -> persistent region @16384 ----
    {
        const u32x4* src = (const u32x4*)img;
        u32x4* dst = (u32x4*)(smem + 16384);
        #pragma unroll
        for (int it = 0; it < 5; it++) {
            const int i = tid + it * 256;
            if (i < IMG_CHUNKS) dst[i] = src[i];
        }
    }

    // ---- per-ray scalars ----
    const float ox = orig[ray * 3 + 0];
    const float oy = orig[ray * 3 + 1];
    const float oz = orig[ray * 3 + 2];
    const float dx = dirs[ray * 3 + 0];
    const float dy = dirs[ray * 3 + 1];
    const float dz = dirs[ray * 3 + 2];
    const float t0v = tmin[ray];
    const float trange = tmax[ray] - t0v;
    const float negdtv = -gvc[64];   // dtv precomputed by prep

    // ---- view-dir encoding (fp32) -> sVde (per-wave) ----
    {
        const float nrm = sqrtf(dx * dx + dy * dy + dz * dz);
        const float inv = 1.0f / (nrm + 1e-8f);
        const float vx = dx * inv, vy = dy * inv, vz = dz * inv;
        if (lane < DVD) {
            float val;
            if (lane < 3) {
                val = (lane == 0) ? vx : ((lane == 1) ? vy : vz);
            } else {
                const int q = lane - 3;
                const int b = q / 6;
                const int r = q - 6 * b;
                const bool isSin = (r < 3);
                const int d = isSin ? r : (r - 3);
                const float comp = (d == 0) ? vx : ((d == 1) ? vy : vz);
                const float a = (float)(1 << b) * comp;
                val = isSin ? sin_fast(a) : cos_fast(a);
            }
            sVde[wave * 28 + lane] = val;
        }
    }
    __syncthreads();   // barrier 1: staging copy + vde writes complete

    const int nfr  = lane & 15;   // n (or m) within a 16-tile
    const int quad = lane >> 4;
    const int cbq  = quad * 16;   // byte col of this lane's k-fragment

    // ---- gv[nt] = gvc[n] + sum_q vde[q] * V1[15+q][n],  n = 4*nfr+nt ----
    float gv[4];
    {
        const f32x4 g0 = *(const f32x4*)&gvc[4 * nfr];
        gv[0] = g0.x; gv[1] = g0.y; gv[2] = g0.z; gv[3] = g0.w;
    }
    #pragma unroll 9
    for (int q = 0; q < DVD; q++) {
        const float e = sVde[wave * 28 + q];
        const f32x4 vv = *(const f32x4*)&V1[(NFEAT + q) * 64 + 4 * nfr];
        gv[0] += e * vv.x; gv[1] += e * vv.y;
        gv[2] += e * vv.z; gv[3] += e * vv.w;
    }

    const float bb2 = b2[0];
    const float bc2 = (nfr < 3) ? c2[nfr] : 0.0f;

    __syncthreads();   // barrier 2: sVde reads done before sE overwrite

    char* const myE = sEc + wave * 4096;   // 32 rows x 128B, swizzled

    const int sl   = lane >> 1;   // local sample 0..31 (enc phase)
    const int half = lane & 1;
    // chain seed frequency: half0 starts at band 0 (f=1), half1 at band 5 (f=32)
    const float fmul = half ? 5.0929581789406507f      // 32 / (2*pi)
                            : 0.15915494309189535f;    //  1 / (2*pi)

    // ---- rotation-recurrence enc state: seed at s=sl, advance 32 samples/qq
    //      via angle-addition with precomputed per-lane delta sincos (the 6
    //      in-loop transcendentals move to this preamble, once) ----
    const float dt32 = (32.0f / 127.0f) * trange;
    const float pdx = dx * dt32, pdy = dy * dt32, pdz = dz * dt32;
    const float tseed = t0v + (float)sl * ((1.0f / 127.0f) * trange);
    float px = ox + dx * tseed, py = oy + dy * tseed, pz = oz + dz * tseed;
    float sx, cx, sy, cy, sz, cz;
    {
        float r;
        r = px * fmul; r -= floorf(r);
        sx = __builtin_amdgcn_sinf(r); cx = __builtin_amdgcn_cosf(r);
        r = py * fmul; r -= floorf(r);
        sy = __builtin_amdgcn_sinf(r); cy = __builtin_amdgcn_cosf(r);
        r = pz * fmul; r -= floorf(r);
        sz = __builtin_amdgcn_sinf(r); cz = __builtin_amdgcn_cosf(r);
    }
    float sDx, cDx, sDy, cDy, sDz, cDz;
    {
        float r;
        r = pdx * fmul; r -= floorf(r);
        sDx = __builtin_amdgcn_sinf(r); cDx = __builtin_amdgcn_cosf(r);
        r = pdy * fmul; r -= floorf(r);
        sDy = __builtin_amdgcn_sinf(r); cDy = __builtin_amdgcn_cosf(r);
        r = pdz * fmul; r -= floorf(r);
        sDz = __builtin_amdgcn_sinf(r); cDz = __builtin_amdgcn_cosf(r);
    }

    #pragma unroll 1
    for (int qq = 0; qq < 4; qq++) {
        // --- positional encodings from state regs -> 4x ds_write_b128 ---
        {
            float wsx = sx, wcx = cx, wsy = sy, wcy = cy, wsz = sz, wcz = cz;
            unsigned e[16] __attribute__((aligned(16)));
            #pragma unroll
            for (int j = 0; j < 5; j++) {
                e[3 * j + 0] = pk2bf(wsx, wsy);
                e[3 * j + 1] = pk2bf(wsz, wcx);
                e[3 * j + 2] = pk2bf(wcy, wcz);
                if (j < 4) {   // double-angle: s'=2sc, c'=1-2s^2
                    const float tx = wsx + wsx, ty = wsy + wsy, tz = wsz + wsz;
                    const float nsx = tx * wcx, nsy = ty * wcy, nsz = tz * wcz;
                    wcx = __builtin_fmaf(-tx, wsx, 1.0f);
                    wcy = __builtin_fmaf(-ty, wsy, 1.0f);
                    wcz = __builtin_fmaf(-tz, wsz, 1.0f);
                    wsx = nsx; wsy = nsy; wsz = nsz;
                }
            }
            e[15] = half ? pk2bf(pz, 1.0f) : pk2bf(px, py);
            #pragma unroll
            for (int w = 0; w < 4; w++)
                *(u32x4*)(myE + XB(sl, half * 64 + w * 16)) =
                    *(const u32x4*)&e[4 * w];
        }
        // --- advance state for next qq (independent; overlaps L1 MFMAs) ---
        {
            const float nsx = __builtin_fmaf(sx, cDx, cx * sDx);
            cx = __builtin_fmaf(cx, cDx, -(sx * sDx)); sx = nsx;
            const float nsy = __builtin_fmaf(sy, cDy, cy * sDy);
            cy = __builtin_fmaf(cy, cDy, -(sy * sDy)); sy = nsy;
            const float nsz = __builtin_fmaf(sz, cDz, cz * sDz);
            cz = __builtin_fmaf(cz, cDz, -(sz * sDz)); sz = nsz;
            px += pdx; py += pdy; pz += pdz;
        }
        // --- layer 1: h = relu(E @ W1 + b1); first-kt MFMA takes C=0 ---
        f32x4 acc1[2][4];
        {
            short8 af[2][2];
            #pragma unroll
            for (int mt = 0; mt < 2; mt++)
                #pragma unroll
                for (int kt = 0; kt < 2; kt++)
                    af[mt][kt] = *(const short8*)(myE + XB(nfr + 16 * mt, cbq + kt * 64));
            __builtin_amdgcn_s_setprio(1);
            #pragma unroll
            for (int nt = 0; nt < 4; nt++) {
                const short8 wf0 = *(const short8*)
                    (sW1tc + XB(nt * 16 + nfr, cbq));
                #pragma unroll
                for (int mt = 0; mt < 2; mt++)
                    acc1[mt][nt] = __builtin_amdgcn_mfma_f32_16x16x32_bf16(
                        af[mt][0], wf0, (f32x4){0.0f, 0.0f, 0.0f, 0.0f}, 0, 0, 0);
                const short8 wf1 = *(const short8*)
                    (sW1tc + XB(nt * 16 + nfr, cbq + 64));
                #pragma unroll
                for (int mt = 0; mt < 2; mt++)
                    acc1[mt][nt] = __builtin_amdgcn_mfma_f32_16x16x32_bf16(
                        af[mt][1], wf1, acc1[mt][nt], 0, 0, 0);
            }
            __builtin_amdgcn_s_setprio(0);
        }
        // packed h epilogue (b64 writes — conflict-clean, R8-proven)
        #pragma unroll
        for (int mt = 0; mt < 2; mt++)
            #pragma unroll
            for (int r = 0; r < 4; r++) {
                const int m = 4 * quad + r + 16 * mt;
                u32x2 hp;
                hp.x = pk2bf(fmaxf(acc1[mt][0][r], 0.0f),
                             fmaxf(acc1[mt][1][r], 0.0f));
                hp.y = pk2bf(fmaxf(acc1[mt][2][r], 0.0f),
                             fmaxf(acc1[mt][3][r], 0.0f));
                *(u32x2*)(myE + XB(m, 8 * nfr)) = hp;
            }
        // --- A-fragments of h (shared by sigma and C GEMMs) ---
        short8 ah[2][2];
        #pragma unroll
        for (int mt = 0; mt < 2; mt++)
            #pragma unroll
            for (int kt = 0; kt < 2; kt++)
                ah[mt][kt] = *(const short8*)(myE + XB(nfr + 16 * mt, cbq + kt * 64));
        // --- sigma: acc2 = b2[0] + h @ w2s (B broadcast from Sm row 0);
        //     store RAW -sigma*dt, exp deferred to the final phase ---
        {
            f32x4 acc2[2];
            acc2[0] = (f32x4){bb2, bb2, bb2, bb2};
            acc2[1] = (f32x4){bb2, bb2, bb2, bb2};
            short8 w2sf[2];
            #pragma unroll
            for (int kt = 0; kt < 2; kt++)
                w2sf[kt] = *(const short8*)&sSm[quad * 8 + kt * 32];
            __builtin_amdgcn_s_setprio(1);
            #pragma unroll
            for (int mt = 0; mt < 2; mt++)
                #pragma unroll
                for (int kt = 0; kt < 2; kt++)
                    acc2[mt] = __builtin_amdgcn_mfma_f32_16x16x32_bf16(
                        ah[mt][kt], w2sf[kt], acc2[mt], 0, 0, 0);
            __builtin_amdgcn_s_setprio(0);
            if (nfr == 0) {
                #pragma unroll
                for (int mt = 0; mt < 2; mt++)
                    #pragma unroll
                    for (int r = 0; r < 4; r++) {
                        const int m = 4 * quad + r + 16 * mt;
                        sOm[wave * 128 + qq * 32 + m] =
                            fmaxf(acc2[mt][r], 0.0f) * negdtv;
                    }
            }
        }
        // --- g = relu(h @ C + gv), nt-split; Ct prow = (2nth+j)*16 + nfr ---
        #pragma unroll
        for (int nth = 0; nth < 2; nth++) {
            f32x4 acc3[2][2];
            #pragma unroll
            for (int mt = 0; mt < 2; mt++)
                #pragma unroll
                for (int j = 0; j < 2; j++) {
                    const float gvi = gv[2 * nth + j];
                    acc3[mt][j] = (f32x4){gvi, gvi, gvi, gvi};
                }
            __builtin_amdgcn_s_setprio(1);
            #pragma unroll
            for (int j = 0; j < 2; j++)
                #pragma unroll
                for (int kt = 0; kt < 2; kt++) {
                    const short8 cf = *(const short8*)
                        (sCtc + XB((2 * nth + j) * 16 + nfr, cbq + kt * 64));
                    #pragma unroll
                    for (int mt = 0; mt < 2; mt++)
                        acc3[mt][j] = __builtin_amdgcn_mfma_f32_16x16x32_bf16(
                            ah[mt][kt], cf, acc3[mt][j], 0, 0, 0);
                }
            __builtin_amdgcn_s_setprio(0);
            #pragma unroll
            for (int mt = 0; mt < 2; mt++)
                #pragma unroll
                for (int r = 0; r < 4; r++) {
                    const int m = 4 * quad + r + 16 * mt;
                    *(unsigned*)(myE + XB(m, 8 * nfr + 4 * nth)) =
                        pk2bf(fmaxf(acc3[mt][0][r], 0.0f),
                              fmaxf(acc3[mt][1][r], 0.0f));
                }
        }
        // --- V2: rgb_pre = g @ V2 + c2; store RAW bf16, sigmoid deferred ---
        {
            f32x4 acc4[2];
            acc4[0] = (f32x4){bc2, bc2, bc2, bc2};
            acc4[1] = (f32x4){bc2, bc2, bc2, bc2};
            short8 agg[2][2];
            #pragma unroll
            for (int mt = 0; mt < 2; mt++)
                #pragma unroll
                for (int kt = 0; kt < 2; kt++)
                    agg[mt][kt] = *(const short8*)(myE + XB(nfr + 16 * mt, cbq + kt * 64));
            const int vr = 1 + ((nfr < 3) ? nfr : 2);
            short8 v2f[2];
            #pragma unroll
            for (int kt = 0; kt < 2; kt++)
                v2f[kt] = *(const short8*)&sSm[vr * 64 + quad * 8 + kt * 32];
            __builtin_amdgcn_s_setprio(1);
            #pragma unroll
            for (int mt = 0; mt < 2; mt++)
                #pragma unroll
                for (int kt = 0; kt < 2; kt++)
                    acc4[mt] = __builtin_amdgcn_mfma_f32_16x16x32_bf16(
                        agg[mt][kt], v2f[kt], acc4[mt], 0, 0, 0);
            __builtin_amdgcn_s_setprio(0);
            if (nfr < 3) {
                #pragma unroll
                for (int mt = 0; mt < 2; mt++)
                    #pragma unroll
                    for (int r = 0; r < 4; r++) {
                        const int m = 4 * quad + r + 16 * mt;
                        stbf(&sRgb[wave * 384 + (qq * 32 + m) * 3 + nfr],
                             acc4[mt][r]);
                    }
            }
        }
    }

    // ---- final: deferred exp/sigmoid + scan + weighted reduce (per wave) ----
    const float om0 = __expf(sOm[wave * 128 + 2 * lane]);
    const float om1 = __expf(sOm[wave * 128 + 2 * lane + 1]);
    const float al0 = 1.0f - om0;
    const float al1 = 1.0f - om1;

    float inc = om0 * om1;
    #pragma unroll
    for (int off = 1; off < 64; off <<= 1) {
        const float q = __shfl_up(inc, off, 64);
        if (lane >= off) inc *= q;
    }
    float Texc = __shfl_up(inc, 1, 64);
    if (lane == 0) Texc = 1.0f;

    const float T0 = Texc;
    const float T1 = Texc * om0;
    const float a0 = (T0 > 1e-4f) ? 1.0f : 0.0f;
    const float a1 = (T1 > 1e-4f) ? 1.0f : 0.0f;
    const float w0 = T0 * al0 * a0;
    const float w1 = T1 * al1 * a1;

    float cr = w0 * sigm(bf2f(sRgb[wave * 384 + (2 * lane) * 3 + 0])) +
               w1 * sigm(bf2f(sRgb[wave * 384 + (2 * lane + 1) * 3 + 0]));
    float cg = w0 * sigm(bf2f(sRgb[wave * 384 + (2 * lane) * 3 + 1])) +
               w1 * sigm(bf2f(sRgb[wave * 384 + (2 * lane + 1) * 3 + 1]));
    float cb = w0 * sigm(bf2f(sRgb[wave * 384 + (2 * lane) * 3 + 2])) +
               w1 * sigm(bf2f(sRgb[wave * 384 + (2 * lane + 1) * 3 + 2]));
    float tp = (a0 > 0.0f ? om0 : 1.0f) * (a1 > 0.0f ? om1 : 1.0f);

    #pragma unroll
    for (int off = 32; off > 0; off >>= 1) {
        cr += __shfl_xor(cr, off, 64);
        cg += __shfl_xor(cg, off, 64);
        cb += __shfl_xor(cb, off, 64);
        tp *= __shfl_xor(tp, off, 64);
    }

    if (lane == 0) {
        out[ray * 3 + 0] = cr;
        out[ray * 3 + 1] = cg;
        out[ray * 3 + 2] = cb;
        out[NRAYS * 3 + ray] = tp;
    }
}

extern "C" void kernel_launch(void* const* d_in, const int* in_sizes, int n_in,
                              void* d_out, int out_size, void* d_ws, size_t ws_size,
                              hipStream_t stream) {
    const float* orig = (const float*)d_in[0];
    const float* dirs = (const float*)d_in[1];
    const float* tmin = (const float*)d_in[2];
    const float* tmax = (const float*)d_in[3];
    const float* W1   = (const float*)d_in[4];
    const float* b1   = (const float*)d_in[5];
    const float* W2   = (const float*)d_in[6];
    const float* b2   = (const float*)d_in[7];
    const float* V1   = (const float*)d_in[8];
    const float* c1   = (const float*)d_in[9];
    const float* V2   = (const float*)d_in[10];
    const float* c2   = (const float*)d_in[11];

    short* img = (short*)d_ws;
    float* gvc = (float*)((char*)d_ws + GVC_OFF);

    prep_kernel<<<35, 256, 0, stream>>>(W1, b1, W2, b2, V1, c1, V2,
                                        tmin, tmax, img, gvc);
    march_kernel<<<NRAYS / 4, 256, 0, stream>>>(orig, dirs, tmin, tmax,
                                                b2, c2, V1, img, gvc,
                                                (float*)d_out);
}

// Round 11
// 113.207 us; speedup vs baseline: 1.0174x; 1.0099x over previous
//
#include <hip/hip_runtime.h>
#include <hip/hip_bf16.h>

#define NRAYS 8192
#define SAMP  128
#define DVD   27
#define NFEAT 15

typedef float  f32x4  __attribute__((ext_vector_type(4)));
typedef short  short8 __attribute__((ext_vector_type(8)));
typedef unsigned int u32x2 __attribute__((ext_vector_type(2)));
typedef unsigned int u32x4 __attribute__((ext_vector_type(4)));

// ---- precomputed weight image in d_ws (shorts = bf16), SWIZZLED LDS LAYOUT --
//  W1t  @byte 0     [64 prow][128B]  swizzled; prow = (n&3)*16 + (n>>2)
//  Ct   @byte 8192  [64 prow][128B]  swizzled; C = W2[:,1:16] @ V1[0:15,:]
//  Sm   @byte 16384 [4][64]shorts : row0 = W2[:,0]; rows1..3 = V2 cols 0..2
//  gvc  @byte 16896 float[64] = c1 + b2[1:16] @ V1[0:15,:] ; gvc[64] = dtv
#define GVC_OFF  16896
#define IMG_CHUNKS 1056     // 16896 / 16

// swizzle: all row-major-128B-row LDS arrays use
//   byte(row, colbyte) = row*128 + (colbyte ^ ((row&7)<<4))
static __device__ __forceinline__ int XB(int row, int cb) {
    return row * 128 + (cb ^ ((row & 7) << 4));
}
// same in short units (for prep): short(row,k) = row*64 + (k ^ ((row&7)<<3))
static __device__ __forceinline__ int XS(int row, int k) {
    return row * 64 + (k ^ ((row & 7) << 3));
}

// fast fp32 -> bf16 (round-half-up)
static __device__ __forceinline__ void stbf(short* p, float x) {
    union { unsigned u; struct { short lo, hi; } s; } v;
    v.u = __float_as_uint(x) + 0x8000u;
    *p = v.s.hi;
}
static __device__ __forceinline__ float bf2f(short s) {
    return __uint_as_float(((unsigned)(unsigned short)s) << 16);
}
// pack two fp32 -> dword of two bf16 (lo -> low half), HW RNE convert
static __device__ __forceinline__ unsigned pk2bf(float lo, float hi) {
    unsigned r;
    asm("v_cvt_pk_bf16_f32 %0, %1, %2" : "=v"(r) : "v"(lo), "v"(hi));
    return r;
}
static __device__ __forceinline__ float sin_fast(float x) {
    float r = x * 0.15915494309189535f;
    r = r - floorf(r);
    return __builtin_amdgcn_sinf(r);
}
static __device__ __forceinline__ float cos_fast(float x) {
    float r = x * 0.15915494309189535f;
    r = r - floorf(r);
    return __builtin_amdgcn_cosf(r);
}
static __device__ __forceinline__ float sigm(float x) {
    return 1.0f / (1.0f + __expf(-x));
}

// E k-layout (shorts within a 64-short row):
//   bands 0..4 : k = 6*b + {sx,sy,sz,cx,cy,cz}   (dwords 0..14, half0)
//   px,py      : k = 30,31                        (dword 15, half0)
//   bands 5..9 : k = 32 + 6*(b-5) + {...}         (dwords 16..30, half1)
//   pz, 1.0    : k = 62,63                        (dword 31, half1; bias col)
static __device__ __forceinline__ int kmap(int r) {
    if (r == 0) return 30;
    if (r == 1) return 31;
    if (r == 2) return 62;
    const int q = r - 3, i = q / 6, c = q - 6 * i;
    return (i < 5 ? 6 * i : 32 + 6 * (i - 5)) + c;
}

// ---------------- prep kernel: build weight image + dtv once ----------------
__global__ void __launch_bounds__(256)
prep_kernel(const float* __restrict__ W1, const float* __restrict__ b1,
            const float* __restrict__ W2, const float* __restrict__ b2,
            const float* __restrict__ V1, const float* __restrict__ c1,
            const float* __restrict__ V2, const float* __restrict__ tmin,
            const float* __restrict__ tmax, short* __restrict__ img,
            float* __restrict__ gvc) {
    if (blockIdx.x == 34) {   // dt reduce: dtv = mean(tmax - tmin) / SAMP
        __shared__ float red[4];
        const int tid = threadIdx.x, lane = tid & 63, wave = tid >> 6;
        const float4* tm0 = (const float4*)tmin;
        const float4* tm1 = (const float4*)tmax;
        float s = 0.0f;
        #pragma unroll
        for (int it = 0; it < 8; it++) {
            const int i = tid + it * 256;
            const float4 a = tm1[i], b = tm0[i];
            s += (a.x - b.x) + (a.y - b.y) + (a.z - b.z) + (a.w - b.w);
        }
        #pragma unroll
        for (int off = 32; off > 0; off >>= 1)
            s += __shfl_xor(s, off, 64);
        if (lane == 0) red[wave] = s;
        __syncthreads();
        if (tid == 0)
            gvc[64] = (red[0] + red[1] + red[2] + red[3]) *
                      (1.0f / ((float)NRAYS * (float)SAMP));
        return;
    }
    const int g = blockIdx.x * 256 + threadIdx.x;   // 0..8703, blocks 0..33
    if (g < 4032) {                       // W1 [63][64] row-major -> swizzled
        const int r = g >> 6, n = g & 63;
        const int prow = (n & 3) * 16 + (n >> 2);
        stbf(&img[XS(prow, kmap(r))], W1[g]);
    } else if (g < 4096) {                // bias column k=63 = b1
        const int n = g - 4032;
        const int prow = (n & 3) * 16 + (n >> 2);
        stbf(&img[XS(prow, 63)], b1[n]);
    } else if (g < 8192) {                // C[k][n] = sum_j W2[k][1+j]*V1[j][n]
        const int i = g - 4096;
        const int k = i >> 6, n = i & 63;
        const int prow = (n & 3) * 16 + (n >> 2);
        float a = 0.0f;
        #pragma unroll
        for (int j = 0; j < 15; j++) a += W2[k * 16 + 1 + j] * V1[j * 64 + n];
        stbf(&img[4096 + XS(prow, k)], a);
    } else if (g < 8256) {                // Sm row0 = sigma weight col
        const int k = g - 8192;
        stbf(&img[8192 + k], W2[k * 16]);
    } else if (g < 8448) {                // Sm rows1..3 = V2 cols
        const int i = g - 8256, c = i >> 6, k = i & 63;
        stbf(&img[8192 + 64 + c * 64 + k], V2[k * 3 + c]);
    } else if (g < 8512) {                // gvc
        const int n = g - 8448;
        float a = c1[n];
        #pragma unroll
        for (int j = 0; j < 15; j++) a += b2[1 + j] * V1[j * 64 + n];
        gvc[n] = a;
    }
}

// LDS layout (38400 B -> 4 blocks/CU, matching the 4-waves/SIMD register cap):
//   sE   @0     [4 waves][32 rows][128B] swizzled
//        (overlay pre-barrier2: sVde @0 [4][28]f)
//   sW1t @16384 [64 prow][128B] swizzled (persistent, fragments re-read per qq)
//   sCt  @24576 [64 prow][128B] swizzled (persistent)
//   sSm  @32768 [4][64]s, sOm @33280 [4][128]f, sRgb @35328 [4][384]s
// NOTE: sOm holds RAW -sigma*dt (exp deferred); sRgb holds RAW pre-sigmoid val.
#define SMEM_BYTES 38400

// (256,4): 4 waves/SIMD needs <=128 unified V+A regs; feasible (R4/R7-proven).
__global__ void __launch_bounds__(256, 4)
march_kernel(const float* __restrict__ orig,
             const float* __restrict__ dirs,
             const float* __restrict__ tmin,
             const float* __restrict__ tmax,
             const float* __restrict__ b2,
             const float* __restrict__ c2,
             const float* __restrict__ V1,
             const short* __restrict__ img,
             const float* __restrict__ gvc,
             float* __restrict__ out) {
    __shared__ __align__(16) char smem[SMEM_BYTES];
    char*  const sEc   = smem;                     // working E tiles
    char*  const sW1tc = smem + 16384;             // persistent
    char*  const sCtc  = smem + 24576;             // persistent
    short* const sSm   = (short*)(smem + 32768);
    float* const sOm   = (float*)(smem + 33280);
    short* const sRgb  = (short*)(smem + 35328);
    float* const sVde  = (float*)(smem);           // overlay, dead at barrier 2

    const int tid  = threadIdx.x;
    const int lane = tid & 63;
    const int wave = tid >> 6;
    const int ray  = blockIdx.x * 4 + wave;

    // ---- weight staging: copy prebuilt image -> persistent region @16384 ----
    {
        const u32x4* src = (const u32x4*)img;
        u32x4* dst = (u32x4*)(smem + 16384);
        #pragma unroll
        for (int it = 0; it < 5; it++) {
            const int i = tid + it * 256;
            if (i < IMG_CHUNKS) dst[i] = src[i];
        }
    }

    // ---- per-ray scalars ----
    const float ox = orig[ray * 3 + 0];
    const float oy = orig[ray * 3 + 1];
    const float oz = orig[ray * 3 + 2];
    const float dx = dirs[ray * 3 + 0];
    const float dy = dirs[ray * 3 + 1];
    const float dz = dirs[ray * 3 + 2];
    const float t0v = tmin[ray];
    const float trange = tmax[ray] - t0v;
    const float negdtv = -gvc[64];   // dtv precomputed by prep

    // ---- view-dir encoding (fp32) -> sVde (per-wave) ----
    {
        const float nrm = sqrtf(dx * dx + dy * dy + dz * dz);
        const float inv = 1.0f / (nrm + 1e-8f);
        const float vx = dx * inv, vy = dy * inv, vz = dz * inv;
        if (lane < DVD) {
            float val;
            if (lane < 3) {
                val = (lane == 0) ? vx : ((lane == 1) ? vy : vz);
            } else {
                const int q = lane - 3;
                const int b = q / 6;
                const int r = q - 6 * b;
                const bool isSin = (r < 3);
                const int d = isSin ? r : (r - 3);
                const float comp = (d == 0) ? vx : ((d == 1) ? vy : vz);
                const float a = (float)(1 << b) * comp;
                val = isSin ? sin_fast(a) : cos_fast(a);
            }
            sVde[wave * 28 + lane] = val;
        }
    }
    __syncthreads();   // barrier 1: staging copy + vde writes complete

    const int nfr  = lane & 15;   // n (or m) within a 16-tile
    const int quad = lane >> 4;
    const int cbq  = quad * 16;   // byte col of this lane's k-fragment

    // ---- gv[nt] = gvc[n] + sum_q vde[q] * V1[15+q][n],  n = 4*nfr+nt ----
    float gv[4];
    {
        const f32x4 g0 = *(const f32x4*)&gvc[4 * nfr];
        gv[0] = g0.x; gv[1] = g0.y; gv[2] = g0.z; gv[3] = g0.w;
    }
    #pragma unroll 9
    for (int q = 0; q < DVD; q++) {
        const float e = sVde[wave * 28 + q];
        const f32x4 vv = *(const f32x4*)&V1[(NFEAT + q) * 64 + 4 * nfr];
        gv[0] += e * vv.x; gv[1] += e * vv.y;
        gv[2] += e * vv.z; gv[3] += e * vv.w;
    }

    const float bb2 = b2[0];
    const float bc2 = (nfr < 3) ? c2[nfr] : 0.0f;

    __syncthreads();   // barrier 2: sVde reads done before sE overwrite

    char* const myE = sEc + wave * 4096;   // 32 rows x 128B, swizzled

    const int sl   = lane >> 1;   // local sample 0..31 (enc phase)
    const int half = lane & 1;
    // chain seed frequency: half0 starts at band 0 (f=1), half1 at band 5 (f=32)
    const float fmul = half ? 5.0929581789406507f      // 32 / (2*pi)
                            : 0.15915494309189535f;    //  1 / (2*pi)

    // ---- rotation-recurrence enc state (seed at s=sl; advance 32/qq) ----
    const float dt32 = (32.0f / 127.0f) * trange;
    const float pdx = dx * dt32, pdy = dy * dt32, pdz = dz * dt32;
    const float tseed = t0v + (float)sl * ((1.0f / 127.0f) * trange);
    float px = ox + dx * tseed, py = oy + dy * tseed, pz = oz + dz * tseed;
    float sx, cx, sy, cy, sz, cz;
    {
        float r;
        r = px * fmul; r -= floorf(r);
        sx = __builtin_amdgcn_sinf(r); cx = __builtin_amdgcn_cosf(r);
        r = py * fmul; r -= floorf(r);
        sy = __builtin_amdgcn_sinf(r); cy = __builtin_amdgcn_cosf(r);
        r = pz * fmul; r -= floorf(r);
        sz = __builtin_amdgcn_sinf(r); cz = __builtin_amdgcn_cosf(r);
    }
    float sDx, cDx, sDy, cDy, sDz, cDz;
    {
        float r;
        r = pdx * fmul; r -= floorf(r);
        sDx = __builtin_amdgcn_sinf(r); cDx = __builtin_amdgcn_cosf(r);
        r = pdy * fmul; r -= floorf(r);
        sDy = __builtin_amdgcn_sinf(r); cDy = __builtin_amdgcn_cosf(r);
        r = pdz * fmul; r -= floorf(r);
        sDz = __builtin_amdgcn_sinf(r); cDz = __builtin_amdgcn_cosf(r);
    }

    // deferred-V2 block: MFMAs on register-held agg, no LDS dependency on the
    // current E tile — runs in the E-write lgkm shadow of the NEXT iteration.
    short8 agg[2][2];
    auto v2_block = [&](int qv) {
        f32x4 acc4[2];
        acc4[0] = (f32x4){bc2, bc2, bc2, bc2};
        acc4[1] = (f32x4){bc2, bc2, bc2, bc2};
        const int vr = 1 + ((nfr < 3) ? nfr : 2);
        short8 v2f[2];
        #pragma unroll
        for (int kt = 0; kt < 2; kt++)
            v2f[kt] = *(const short8*)&sSm[vr * 64 + quad * 8 + kt * 32];
        #pragma unroll
        for (int mt = 0; mt < 2; mt++)
            #pragma unroll
            for (int kt = 0; kt < 2; kt++)
                acc4[mt] = __builtin_amdgcn_mfma_f32_16x16x32_bf16(
                    agg[mt][kt], v2f[kt], acc4[mt], 0, 0, 0);
        if (nfr < 3) {
            #pragma unroll
            for (int mt = 0; mt < 2; mt++)
                #pragma unroll
                for (int r = 0; r < 4; r++) {
                    const int m = 4 * quad + r + 16 * mt;
                    stbf(&sRgb[wave * 384 + (qv * 32 + m) * 3 + nfr],
                         acc4[mt][r]);
                }
        }
    };

    #pragma unroll 1
    for (int qq = 0; qq < 4; qq++) {
        // --- positional encodings from state regs -> 4x ds_write_b128 ---
        {
            float wsx = sx, wcx = cx, wsy = sy, wcy = cy, wsz = sz, wcz = cz;
            unsigned e[16] __attribute__((aligned(16)));
            #pragma unroll
            for (int j = 0; j < 5; j++) {
                e[3 * j + 0] = pk2bf(wsx, wsy);
                e[3 * j + 1] = pk2bf(wsz, wcx);
                e[3 * j + 2] = pk2bf(wcy, wcz);
                if (j < 4) {   // double-angle: s'=2sc, c'=1-2s^2
                    const float tx = wsx + wsx, ty = wsy + wsy, tz = wsz + wsz;
                    const float nsx = tx * wcx, nsy = ty * wcy, nsz = tz * wcz;
                    wcx = __builtin_fmaf(-tx, wsx, 1.0f);
                    wcy = __builtin_fmaf(-ty, wsy, 1.0f);
                    wcz = __builtin_fmaf(-tz, wsz, 1.0f);
                    wsx = nsx; wsy = nsy; wsz = nsz;
                }
            }
            e[15] = half ? pk2bf(pz, 1.0f) : pk2bf(px, py);
            #pragma unroll
            for (int w = 0; w < 4; w++)
                *(u32x4*)(myE + XB(sl, half * 64 + w * 16)) =
                    *(const u32x4*)&e[4 * w];
        }
        // --- advance state for next qq (independent; overlaps MFMAs) ---
        {
            const float nsx = __builtin_fmaf(sx, cDx, cx * sDx);
            cx = __builtin_fmaf(cx, cDx, -(sx * sDx)); sx = nsx;
            const float nsy = __builtin_fmaf(sy, cDy, cy * sDy);
            cy = __builtin_fmaf(cy, cDy, -(sy * sDy)); sy = nsy;
            const float nsz = __builtin_fmaf(sz, cDz, cz * sDz);
            cz = __builtin_fmaf(cz, cDz, -(sz * sDz)); sz = nsz;
            px += pdx; py += pdy; pz += pdz;
        }
        // --- deferred V2 of previous qq (register-only; fills E-write shadow)
        if (qq > 0) v2_block(qq - 1);
        // --- layer 1: h = relu(E @ W1 + b1); first-kt MFMA takes C=0 ---
        f32x4 acc1[2][4];
        {
            short8 af[2][2];
            #pragma unroll
            for (int mt = 0; mt < 2; mt++)
                #pragma unroll
                for (int kt = 0; kt < 2; kt++)
                    af[mt][kt] = *(const short8*)(myE + XB(nfr + 16 * mt, cbq + kt * 64));
            __builtin_amdgcn_s_setprio(1);
            #pragma unroll
            for (int nt = 0; nt < 4; nt++) {
                const short8 wf0 = *(const short8*)
                    (sW1tc + XB(nt * 16 + nfr, cbq));
                #pragma unroll
                for (int mt = 0; mt < 2; mt++)
                    acc1[mt][nt] = __builtin_amdgcn_mfma_f32_16x16x32_bf16(
                        af[mt][0], wf0, (f32x4){0.0f, 0.0f, 0.0f, 0.0f}, 0, 0, 0);
                const short8 wf1 = *(const short8*)
                    (sW1tc + XB(nt * 16 + nfr, cbq + 64));
                #pragma unroll
                for (int mt = 0; mt < 2; mt++)
                    acc1[mt][nt] = __builtin_amdgcn_mfma_f32_16x16x32_bf16(
                        af[mt][1], wf1, acc1[mt][nt], 0, 0, 0);
            }
            __builtin_amdgcn_s_setprio(0);
        }
        // packed h epilogue (b64 writes — conflict-clean)
        #pragma unroll
        for (int mt = 0; mt < 2; mt++)
            #pragma unroll
            for (int r = 0; r < 4; r++) {
                const int m = 4 * quad + r + 16 * mt;
                u32x2 hp;
                hp.x = pk2bf(fmaxf(acc1[mt][0][r], 0.0f),
                             fmaxf(acc1[mt][1][r], 0.0f));
                hp.y = pk2bf(fmaxf(acc1[mt][2][r], 0.0f),
                             fmaxf(acc1[mt][3][r], 0.0f));
                *(u32x2*)(myE + XB(m, 8 * nfr)) = hp;
            }
        // --- A-fragments of h (shared by sigma and C GEMMs) ---
        short8 ah[2][2];
        #pragma unroll
        for (int mt = 0; mt < 2; mt++)
            #pragma unroll
            for (int kt = 0; kt < 2; kt++)
                ah[mt][kt] = *(const short8*)(myE + XB(nfr + 16 * mt, cbq + kt * 64));
        // --- sigma: acc2 = b2[0] + h @ w2s (B broadcast from Sm row 0);
        //     store RAW -sigma*dt, exp deferred (acc2 dead before acc3) ---
        {
            f32x4 acc2[2];
            acc2[0] = (f32x4){bb2, bb2, bb2, bb2};
            acc2[1] = (f32x4){bb2, bb2, bb2, bb2};
            short8 w2sf[2];
            #pragma unroll
            for (int kt = 0; kt < 2; kt++)
                w2sf[kt] = *(const short8*)&sSm[quad * 8 + kt * 32];
            __builtin_amdgcn_s_setprio(1);
            #pragma unroll
            for (int mt = 0; mt < 2; mt++)
                #pragma unroll
                for (int kt = 0; kt < 2; kt++)
                    acc2[mt] = __builtin_amdgcn_mfma_f32_16x16x32_bf16(
                        ah[mt][kt], w2sf[kt], acc2[mt], 0, 0, 0);
            __builtin_amdgcn_s_setprio(0);
            if (nfr == 0) {
                #pragma unroll
                for (int mt = 0; mt < 2; mt++)
                    #pragma unroll
                    for (int r = 0; r < 4; r++) {
                        const int m = 4 * quad + r + 16 * mt;
                        sOm[wave * 128 + qq * 32 + m] =
                            fmaxf(acc2[mt][r], 0.0f) * negdtv;
                    }
            }
        }
        // --- g = relu(h @ C + gv), FUSED acc3[2][4]; b64 epilogue (clean) ---
        {
            f32x4 acc3[2][4];
            #pragma unroll
            for (int mt = 0; mt < 2; mt++)
                #pragma unroll
                for (int nt = 0; nt < 4; nt++)
                    acc3[mt][nt] = (f32x4){gv[nt], gv[nt], gv[nt], gv[nt]};
            __builtin_amdgcn_s_setprio(1);
            #pragma unroll
            for (int nt = 0; nt < 4; nt++)
                #pragma unroll
                for (int kt = 0; kt < 2; kt++) {
                    const short8 cf = *(const short8*)
                        (sCtc + XB(nt * 16 + nfr, cbq + kt * 64));
                    #pragma unroll
                    for (int mt = 0; mt < 2; mt++)
                        acc3[mt][nt] = __builtin_amdgcn_mfma_f32_16x16x32_bf16(
                            ah[mt][kt], cf, acc3[mt][nt], 0, 0, 0);
                }
            __builtin_amdgcn_s_setprio(0);
            #pragma unroll
            for (int mt = 0; mt < 2; mt++)
                #pragma unroll
                for (int r = 0; r < 4; r++) {
                    const int m = 4 * quad + r + 16 * mt;
                    u32x2 gp;
                    gp.x = pk2bf(fmaxf(acc3[mt][0][r], 0.0f),
                                 fmaxf(acc3[mt][1][r], 0.0f));
                    gp.y = pk2bf(fmaxf(acc3[mt][2][r], 0.0f),
                                 fmaxf(acc3[mt][3][r], 0.0f));
                    *(u32x2*)(myE + XB(m, 8 * nfr)) = gp;
                }
        }
        // --- read g fragments now; V2 MFMAs deferred to next iteration ---
        #pragma unroll
        for (int mt = 0; mt < 2; mt++)
            #pragma unroll
            for (int kt = 0; kt < 2; kt++)
                agg[mt][kt] = *(const short8*)(myE + XB(nfr + 16 * mt, cbq + kt * 64));
    }
    v2_block(3);   // tail

    // ---- final: deferred exp/sigmoid + scan + weighted reduce (per wave) ----
    const float om0 = __expf(sOm[wave * 128 + 2 * lane]);
    const float om1 = __expf(sOm[wave * 128 + 2 * lane + 1]);
    const float al0 = 1.0f - om0;
    const float al1 = 1.0f - om1;

    float inc = om0 * om1;
    #pragma unroll
    for (int off = 1; off < 64; off <<= 1) {
        const float q = __shfl_up(inc, off, 64);
        if (lane >= off) inc *= q;
    }
    float Texc = __shfl_up(inc, 1, 64);
    if (lane == 0) Texc = 1.0f;

    const float T0 = Texc;
    const float T1 = Texc * om0;
    const float a0 = (T0 > 1e-4f) ? 1.0f : 0.0f;
    const float a1 = (T1 > 1e-4f) ? 1.0f : 0.0f;
    const float w0 = T0 * al0 * a0;
    const float w1 = T1 * al1 * a1;

    float cr = w0 * sigm(bf2f(sRgb[wave * 384 + (2 * lane) * 3 + 0])) +
               w1 * sigm(bf2f(sRgb[wave * 384 + (2 * lane + 1) * 3 + 0]));
    float cg = w0 * sigm(bf2f(sRgb[wave * 384 + (2 * lane) * 3 + 1])) +
               w1 * sigm(bf2f(sRgb[wave * 384 + (2 * lane + 1) * 3 + 1]));
    float cb = w0 * sigm(bf2f(sRgb[wave * 384 + (2 * lane) * 3 + 2])) +
               w1 * sigm(bf2f(sRgb[wave * 384 + (2 * lane + 1) * 3 + 2]));
    float tp = (a0 > 0.0f ? om0 : 1.0f) * (a1 > 0.0f ? om1 : 1.0f);

    #pragma unroll
    for (int off = 32; off > 0; off >>= 1) {
        cr += __shfl_xor(cr, off, 64);
        cg += __shfl_xor(cg, off, 64);
        cb += __shfl_xor(cb, off, 64);
        tp *= __shfl_xor(tp, off, 64);
    }

    if (lane == 0) {
        out[ray * 3 + 0] = cr;
        out[ray * 3 + 1] = cg;
        out[ray * 3 + 2] = cb;
        out[NRAYS * 3 + ray] = tp;
    }
}

extern "C" void kernel_launch(void* const* d_in, const int* in_sizes, int n_in,
                              void* d_out, int out_size, void* d_ws, size_t ws_size,
                              hipStream_t stream) {
    const float* orig = (const float*)d_in[0];
    const float* dirs = (const float*)d_in[1];
    const float* tmin = (const float*)d_in[2];
    const float* tmax = (const float*)d_in[3];
    const float* W1   = (const float*)d_in[4];
    const float* b1   = (const float*)d_in[5];
    const float* W2   = (const float*)d_in[6];
    const float* b2   = (const float*)d_in[7];
    const float* V1   = (const float*)d_in[8];
    const float* c1   = (const float*)d_in[9];
    const float* V2   = (const float*)d_in[10];
    const float* c2   = (const float*)d_in[11];

    short* img = (short*)d_ws;
    float* gvc = (float*)((char*)d_ws + GVC_OFF);

    prep_kernel<<<35, 256, 0, stream>>>(W1, b1, W2, b2, V1, c1, V2,
                                        tmin, tmax, img, gvc);
    march_kernel<<<NRAYS / 4, 256, 0, stream>>>(orig, dirs, tmin, tmax,
                                                b2, c2, V1, img, gvc,
                                                (float*)d_out);
}

// Round 12
// 112.934 us; speedup vs baseline: 1.0198x; 1.0024x over previous
//
#include <hip/hip_runtime.h>
#include <hip/hip_bf16.h>

#define NRAYS 8192
#define SAMP  128
#define DVD   27
#define NFEAT 15

typedef float  f32x4  __attribute__((ext_vector_type(4)));
typedef short  short8 __attribute__((ext_vector_type(8)));
typedef unsigned int u32x2 __attribute__((ext_vector_type(2)));
typedef unsigned int u32x4 __attribute__((ext_vector_type(4)));

// ---- precomputed weight image in d_ws (shorts = bf16), SWIZZLED LDS LAYOUT --
//  W1t  @byte 0     [64 prow][128B]  swizzled; prow = (n&3)*16 + (n>>2)
//  Ct   @byte 8192  [64 prow][128B]  swizzled; C = W2[:,1:16] @ V1[0:15,:]
//  Sm   @byte 16384 [4][64]shorts : row0 = W2[:,0]; rows1..3 = V2 cols 0..2
//  gvc  @byte 16896 float[64] = c1 + b2[1:16] @ V1[0:15,:] ; gvc[64] = dtv
#define GVC_OFF  16896
#define IMG_CHUNKS 1056     // 16896 / 16

// swizzle: all row-major-128B-row LDS arrays use
//   byte(row, colbyte) = row*128 + (colbyte ^ ((row&7)<<4))
static __device__ __forceinline__ int XB(int row, int cb) {
    return row * 128 + (cb ^ ((row & 7) << 4));
}
// same in short units (for prep): short(row,k) = row*64 + (k ^ ((row&7)<<3))
static __device__ __forceinline__ int XS(int row, int k) {
    return row * 64 + (k ^ ((row & 7) << 3));
}

// fast fp32 -> bf16 (round-half-up)
static __device__ __forceinline__ void stbf(short* p, float x) {
    union { unsigned u; struct { short lo, hi; } s; } v;
    v.u = __float_as_uint(x) + 0x8000u;
    *p = v.s.hi;
}
static __device__ __forceinline__ float bf2f(short s) {
    return __uint_as_float(((unsigned)(unsigned short)s) << 16);
}
// pack two fp32 -> dword of two bf16 (lo -> low half), HW RNE convert
static __device__ __forceinline__ unsigned pk2bf(float lo, float hi) {
    unsigned r;
    asm("v_cvt_pk_bf16_f32 %0, %1, %2" : "=v"(r) : "v"(lo), "v"(hi));
    return r;
}
static __device__ __forceinline__ float sin_fast(float x) {
    float r = x * 0.15915494309189535f;
    r = r - floorf(r);
    return __builtin_amdgcn_sinf(r);
}
static __device__ __forceinline__ float cos_fast(float x) {
    float r = x * 0.15915494309189535f;
    r = r - floorf(r);
    return __builtin_amdgcn_cosf(r);
}
static __device__ __forceinline__ float sigm(float x) {
    return 1.0f / (1.0f + __expf(-x));
}

// E k-layout (shorts within a 64-short row):
//   bands 0..4 : k = 6*b + {sx,sy,sz,cx,cy,cz}   (dwords 0..14, half0)
//   px,py      : k = 30,31                        (dword 15, half0)
//   bands 5..9 : k = 32 + 6*(b-5) + {...}         (dwords 16..30, half1)
//   pz, 1.0    : k = 62,63                        (dword 31, half1; bias col)
static __device__ __forceinline__ int kmap(int r) {
    if (r == 0) return 30;
    if (r == 1) return 31;
    if (r == 2) return 62;
    const int q = r - 3, i = q / 6, c = q - 6 * i;
    return (i < 5 ? 6 * i : 32 + 6 * (i - 5)) + c;
}

// ---------------- prep kernel: build weight image + dtv once ----------------
__global__ void __launch_bounds__(256)
prep_kernel(const float* __restrict__ W1, const float* __restrict__ b1,
            const float* __restrict__ W2, const float* __restrict__ b2,
            const float* __restrict__ V1, const float* __restrict__ c1,
            const float* __restrict__ V2, const float* __restrict__ tmin,
            const float* __restrict__ tmax, short* __restrict__ img,
            float* __restrict__ gvc) {
    if (blockIdx.x == 34) {   // dt reduce: dtv = mean(tmax - tmin) / SAMP
        __shared__ float red[4];
        const int tid = threadIdx.x, lane = tid & 63, wave = tid >> 6;
        const float4* tm0 = (const float4*)tmin;
        const float4* tm1 = (const float4*)tmax;
        float s = 0.0f;
        #pragma unroll
        for (int it = 0; it < 8; it++) {
            const int i = tid + it * 256;
            const float4 a = tm1[i], b = tm0[i];
            s += (a.x - b.x) + (a.y - b.y) + (a.z - b.z) + (a.w - b.w);
        }
        #pragma unroll
        for (int off = 32; off > 0; off >>= 1)
            s += __shfl_xor(s, off, 64);
        if (lane == 0) red[wave] = s;
        __syncthreads();
        if (tid == 0)
            gvc[64] = (red[0] + red[1] + red[2] + red[3]) *
                      (1.0f / ((float)NRAYS * (float)SAMP));
        return;
    }
    const int g = blockIdx.x * 256 + threadIdx.x;   // 0..8703, blocks 0..33
    if (g < 4032) {                       // W1 [63][64] row-major -> swizzled
        const int r = g >> 6, n = g & 63;
        const int prow = (n & 3) * 16 + (n >> 2);
        stbf(&img[XS(prow, kmap(r))], W1[g]);
    } else if (g < 4096) {                // bias column k=63 = b1
        const int n = g - 4032;
        const int prow = (n & 3) * 16 + (n >> 2);
        stbf(&img[XS(prow, 63)], b1[n]);
    } else if (g < 8192) {                // C[k][n] = sum_j W2[k][1+j]*V1[j][n]
        const int i = g - 4096;
        const int k = i >> 6, n = i & 63;
        const int prow = (n & 3) * 16 + (n >> 2);
        float a = 0.0f;
        #pragma unroll
        for (int j = 0; j < 15; j++) a += W2[k * 16 + 1 + j] * V1[j * 64 + n];
        stbf(&img[4096 + XS(prow, k)], a);
    } else if (g < 8256) {                // Sm row0 = sigma weight col
        const int k = g - 8192;
        stbf(&img[8192 + k], W2[k * 16]);
    } else if (g < 8448) {                // Sm rows1..3 = V2 cols
        const int i = g - 8256, c = i >> 6, k = i & 63;
        stbf(&img[8192 + 64 + c * 64 + k], V2[k * 3 + c]);
    } else if (g < 8512) {                // gvc
        const int n = g - 8448;
        float a = c1[n];
        #pragma unroll
        for (int j = 0; j < 15; j++) a += b2[1 + j] * V1[j * 64 + n];
        gvc[n] = a;
    }
}

// LDS layout (38848 B -> 4 blocks/CU, matching the 4-waves/SIMD register cap):
//   sE   @0     [4 waves][32 rows][128B] swizzled (wave-private working tiles)
//   sW1t @16384 [64 prow][128B] swizzled (persistent, fragments re-read per qq)
//   sCt  @24576 [64 prow][128B] swizzled (persistent)
//   sSm  @32768 [4][64]s, sOm @33280 [4][128]f, sRgb @35328 [4][384]s
//   sVde @38400 [4][28]f  (persistent, wave-private -> NO barrier needed
//        between vde/gv phase and E-writes; only barrier 1 (staging) remains)
// NOTE: sOm holds RAW -sigma*dt (exp deferred); sRgb holds RAW pre-sigmoid val.
#define SMEM_BYTES 38848

// (256,4): 4 waves/SIMD needs <=128 unified V+A regs; feasible (R4/R7-proven).
__global__ void __launch_bounds__(256, 4)
march_kernel(const float* __restrict__ orig,
             const float* __restrict__ dirs,
             const float* __restrict__ tmin,
             const float* __restrict__ tmax,
             const float* __restrict__ b2,
             const float* __restrict__ c2,
             const float* __restrict__ V1,
             const short* __restrict__ img,
             const float* __restrict__ gvc,
             float* __restrict__ out) {
    __shared__ __align__(16) char smem[SMEM_BYTES];
    char*  const sEc   = smem;                     // working E tiles
    char*  const sW1tc = smem + 16384;             // persistent
    char*  const sCtc  = smem + 24576;             // persistent
    short* const sSm   = (short*)(smem + 32768);
    float* const sOm   = (float*)(smem + 33280);
    short* const sRgb  = (short*)(smem + 35328);
    float* const sVde  = (float*)(smem + 38400);   // persistent, wave-private

    const int tid  = threadIdx.x;
    const int lane = tid & 63;
    const int wave = tid >> 6;
    const int ray  = blockIdx.x * 4 + wave;

    // ---- weight staging: copy prebuilt image -> persistent region @16384 ----
    {
        const u32x4* src = (const u32x4*)img;
        u32x4* dst = (u32x4*)(smem + 16384);
        #pragma unroll
        for (int it = 0; it < 5; it++) {
            const int i = tid + it * 256;
            if (i < IMG_CHUNKS) dst[i] = src[i];
        }
    }

    // ---- per-ray scalars ----
    const float ox = orig[ray * 3 + 0];
    const float oy = orig[ray * 3 + 1];
    const float oz = orig[ray * 3 + 2];
    const float dx = dirs[ray * 3 + 0];
    const float dy = dirs[ray * 3 + 1];
    const float dz = dirs[ray * 3 + 2];
    const float t0v = tmin[ray];
    const float trange = tmax[ray] - t0v;
    const float negdtv = -gvc[64];   // dtv precomputed by prep

    // ---- view-dir encoding (fp32) -> sVde (wave-private, no barrier after) --
    {
        const float nrm = sqrtf(dx * dx + dy * dy + dz * dz);
        const float inv = 1.0f / (nrm + 1e-8f);
        const float vx = dx * inv, vy = dy * inv, vz = dz * inv;
        if (lane < DVD) {
            float val;
            if (lane < 3) {
                val = (lane == 0) ? vx : ((lane == 1) ? vy : vz);
            } else {
                const int q = lane - 3;
                const int b = q / 6;
                const int r = q - 6 * b;
                const bool isSin = (r < 3);
                const int d = isSin ? r : (r - 3);
                const float comp = (d == 0) ? vx : ((d == 1) ? vy : vz);
                const float a = (float)(1 << b) * comp;
                val = isSin ? sin_fast(a) : cos_fast(a);
            }
            sVde[wave * 28 + lane] = val;
        }
    }
    __syncthreads();   // barrier 1 (ONLY barrier): staging copy complete

    const int nfr  = lane & 15;   // n (or m) within a 16-tile
    const int quad = lane >> 4;
    const int cbq  = quad * 16;   // byte col of this lane's k-fragment

    // ---- gv[nt] = gvc[n] + sum_q vde[q] * V1[15+q][n],  n = 4*nfr+nt ----
    float gv[4];
    {
        const f32x4 g0 = *(const f32x4*)&gvc[4 * nfr];
        gv[0] = g0.x; gv[1] = g0.y; gv[2] = g0.z; gv[3] = g0.w;
    }
    #pragma unroll 9
    for (int q = 0; q < DVD; q++) {
        const float e = sVde[wave * 28 + q];
        const f32x4 vv = *(const f32x4*)&V1[(NFEAT + q) * 64 + 4 * nfr];
        gv[0] += e * vv.x; gv[1] += e * vv.y;
        gv[2] += e * vv.z; gv[3] += e * vv.w;
    }

    const float bb2 = b2[0];
    const float bc2 = (nfr < 3) ? c2[nfr] : 0.0f;

    char* const myE = sEc + wave * 4096;   // 32 rows x 128B, swizzled

    const int sl   = lane >> 1;   // local sample 0..31 (enc phase)
    const int half = lane & 1;
    // chain seed frequency: half0 starts at band 0 (f=1), half1 at band 5 (f=32)
    const float fmul = half ? 5.0929581789406507f      // 32 / (2*pi)
                            : 0.15915494309189535f;    //  1 / (2*pi)

    // ---- rotation-recurrence enc state (seed at s=sl; advance 32/qq) ----
    const float dt32 = (32.0f / 127.0f) * trange;
    const float pdx = dx * dt32, pdy = dy * dt32, pdz = dz * dt32;
    const float tseed = t0v + (float)sl * ((1.0f / 127.0f) * trange);
    float px = ox + dx * tseed, py = oy + dy * tseed, pz = oz + dz * tseed;
    float sx, cx, sy, cy, sz, cz;
    {
        float r;
        r = px * fmul; r -= floorf(r);
        sx = __builtin_amdgcn_sinf(r); cx = __builtin_amdgcn_cosf(r);
        r = py * fmul; r -= floorf(r);
        sy = __builtin_amdgcn_sinf(r); cy = __builtin_amdgcn_cosf(r);
        r = pz * fmul; r -= floorf(r);
        sz = __builtin_amdgcn_sinf(r); cz = __builtin_amdgcn_cosf(r);
    }
    float sDx, cDx, sDy, cDy, sDz, cDz;
    {
        float r;
        r = pdx * fmul; r -= floorf(r);
        sDx = __builtin_amdgcn_sinf(r); cDx = __builtin_amdgcn_cosf(r);
        r = pdy * fmul; r -= floorf(r);
        sDy = __builtin_amdgcn_sinf(r); cDy = __builtin_amdgcn_cosf(r);
        r = pdz * fmul; r -= floorf(r);
        sDz = __builtin_amdgcn_sinf(r); cDz = __builtin_amdgcn_cosf(r);
    }

    // deferred-V2 block: MFMAs on register-held agg, no LDS dependency on the
    // current E tile — runs in the E-write lgkm shadow of the NEXT iteration.
    short8 agg[2][2];
    auto v2_block = [&](int qv) {
        f32x4 acc4[2];
        acc4[0] = (f32x4){bc2, bc2, bc2, bc2};
        acc4[1] = (f32x4){bc2, bc2, bc2, bc2};
        const int vr = 1 + ((nfr < 3) ? nfr : 2);
        short8 v2f[2];
        #pragma unroll
        for (int kt = 0; kt < 2; kt++)
            v2f[kt] = *(const short8*)&sSm[vr * 64 + quad * 8 + kt * 32];
        #pragma unroll
        for (int mt = 0; mt < 2; mt++)
            #pragma unroll
            for (int kt = 0; kt < 2; kt++)
                acc4[mt] = __builtin_amdgcn_mfma_f32_16x16x32_bf16(
                    agg[mt][kt], v2f[kt], acc4[mt], 0, 0, 0);
        if (nfr < 3) {
            #pragma unroll
            for (int mt = 0; mt < 2; mt++)
                #pragma unroll
                for (int r = 0; r < 4; r++) {
                    const int m = 4 * quad + r + 16 * mt;
                    stbf(&sRgb[wave * 384 + (qv * 32 + m) * 3 + nfr],
                         acc4[mt][r]);
                }
        }
    };

    #pragma unroll 1
    for (int qq = 0; qq < 4; qq++) {
        // --- positional encodings from state regs -> 4x ds_write_b128 ---
        {
            float wsx = sx, wcx = cx, wsy = sy, wcy = cy, wsz = sz, wcz = cz;
            unsigned e[16] __attribute__((aligned(16)));
            #pragma unroll
            for (int j = 0; j < 5; j++) {
                e[3 * j + 0] = pk2bf(wsx, wsy);
                e[3 * j + 1] = pk2bf(wsz, wcx);
                e[3 * j + 2] = pk2bf(wcy, wcz);
                if (j < 4) {   // double-angle: s'=2sc, c'=1-2s^2
                    const float tx = wsx + wsx, ty = wsy + wsy, tz = wsz + wsz;
                    const float nsx = tx * wcx, nsy = ty * wcy, nsz = tz * wcz;
                    wcx = __builtin_fmaf(-tx, wsx, 1.0f);
                    wcy = __builtin_fmaf(-ty, wsy, 1.0f);
                    wcz = __builtin_fmaf(-tz, wsz, 1.0f);
                    wsx = nsx; wsy = nsy; wsz = nsz;
                }
            }
            e[15] = half ? pk2bf(pz, 1.0f) : pk2bf(px, py);
            #pragma unroll
            for (int w = 0; w < 4; w++)
                *(u32x4*)(myE + XB(sl, half * 64 + w * 16)) =
                    *(const u32x4*)&e[4 * w];
        }
        // --- advance state for next qq (independent; overlaps MFMAs) ---
        {
            const float nsx = __builtin_fmaf(sx, cDx, cx * sDx);
            cx = __builtin_fmaf(cx, cDx, -(sx * sDx)); sx = nsx;
            const float nsy = __builtin_fmaf(sy, cDy, cy * sDy);
            cy = __builtin_fmaf(cy, cDy, -(sy * sDy)); sy = nsy;
            const float nsz = __builtin_fmaf(sz, cDz, cz * sDz);
            cz = __builtin_fmaf(cz, cDz, -(sz * sDz)); sz = nsz;
            px += pdx; py += pdy; pz += pdz;
        }
        // --- deferred V2 of previous qq (register-only; fills E-write shadow)
        if (qq > 0) v2_block(qq - 1);
        // --- layer 1: h = relu(E @ W1 + b1); first-kt MFMA takes C=0 ---
        f32x4 acc1[2][4];
        {
            short8 af[2][2];
            #pragma unroll
            for (int mt = 0; mt < 2; mt++)
                #pragma unroll
                for (int kt = 0; kt < 2; kt++)
                    af[mt][kt] = *(const short8*)(myE + XB(nfr + 16 * mt, cbq + kt * 64));
            __builtin_amdgcn_s_setprio(1);
            #pragma unroll
            for (int nt = 0; nt < 4; nt++) {
                const short8 wf0 = *(const short8*)
                    (sW1tc + XB(nt * 16 + nfr, cbq));
                #pragma unroll
                for (int mt = 0; mt < 2; mt++)
                    acc1[mt][nt] = __builtin_amdgcn_mfma_f32_16x16x32_bf16(
                        af[mt][0], wf0, (f32x4){0.0f, 0.0f, 0.0f, 0.0f}, 0, 0, 0);
                const short8 wf1 = *(const short8*)
                    (sW1tc + XB(nt * 16 + nfr, cbq + 64));
                #pragma unroll
                for (int mt = 0; mt < 2; mt++)
                    acc1[mt][nt] = __builtin_amdgcn_mfma_f32_16x16x32_bf16(
                        af[mt][1], wf1, acc1[mt][nt], 0, 0, 0);
            }
            __builtin_amdgcn_s_setprio(0);
        }
        // packed h epilogue (b64 writes — conflict-clean)
        #pragma unroll
        for (int mt = 0; mt < 2; mt++)
            #pragma unroll
            for (int r = 0; r < 4; r++) {
                const int m = 4 * quad + r + 16 * mt;
                u32x2 hp;
                hp.x = pk2bf(fmaxf(acc1[mt][0][r], 0.0f),
                             fmaxf(acc1[mt][1][r], 0.0f));
                hp.y = pk2bf(fmaxf(acc1[mt][2][r], 0.0f),
                             fmaxf(acc1[mt][3][r], 0.0f));
                *(u32x2*)(myE + XB(m, 8 * nfr)) = hp;
            }
        // --- A-fragments of h (shared by sigma and C GEMMs) ---
        short8 ah[2][2];
        #pragma unroll
        for (int mt = 0; mt < 2; mt++)
            #pragma unroll
            for (int kt = 0; kt < 2; kt++)
                ah[mt][kt] = *(const short8*)(myE + XB(nfr + 16 * mt, cbq + kt * 64));
        // --- sigma: acc2 = b2[0] + h @ w2s (B broadcast from Sm row 0);
        //     store RAW -sigma*dt, exp deferred (acc2 dead before acc3) ---
        {
            f32x4 acc2[2];
            acc2[0] = (f32x4){bb2, bb2, bb2, bb2};
            acc2[1] = (f32x4){bb2, bb2, bb2, bb2};
            short8 w2sf[2];
            #pragma unroll
            for (int kt = 0; kt < 2; kt++)
                w2sf[kt] = *(const short8*)&sSm[quad * 8 + kt * 32];
            __builtin_amdgcn_s_setprio(1);
            #pragma unroll
            for (int mt = 0; mt < 2; mt++)
                #pragma unroll
                for (int kt = 0; kt < 2; kt++)
                    acc2[mt] = __builtin_amdgcn_mfma_f32_16x16x32_bf16(
                        ah[mt][kt], w2sf[kt], acc2[mt], 0, 0, 0);
            __builtin_amdgcn_s_setprio(0);
            if (nfr == 0) {
                #pragma unroll
                for (int mt = 0; mt < 2; mt++)
                    #pragma unroll
                    for (int r = 0; r < 4; r++) {
                        const int m = 4 * quad + r + 16 * mt;
                        sOm[wave * 128 + qq * 32 + m] =
                            fmaxf(acc2[mt][r], 0.0f) * negdtv;
                    }
            }
        }
        // --- g = relu(h @ C + gv), FUSED acc3[2][4]; b64 epilogue (clean) ---
        {
            f32x4 acc3[2][4];
            #pragma unroll
            for (int mt = 0; mt < 2; mt++)
                #pragma unroll
                for (int nt = 0; nt < 4; nt++)
                    acc3[mt][nt] = (f32x4){gv[nt], gv[nt], gv[nt], gv[nt]};
            __builtin_amdgcn_s_setprio(1);
            #pragma unroll
            for (int nt = 0; nt < 4; nt++)
                #pragma unroll
                for (int kt = 0; kt < 2; kt++) {
                    const short8 cf = *(const short8*)
                        (sCtc + XB(nt * 16 + nfr, cbq + kt * 64));
                    #pragma unroll
                    for (int mt = 0; mt < 2; mt++)
                        acc3[mt][nt] = __builtin_amdgcn_mfma_f32_16x16x32_bf16(
                            ah[mt][kt], cf, acc3[mt][nt], 0, 0, 0);
                }
            __builtin_amdgcn_s_setprio(0);
            #pragma unroll
            for (int mt = 0; mt < 2; mt++)
                #pragma unroll
                for (int r = 0; r < 4; r++) {
                    const int m = 4 * quad + r + 16 * mt;
                    u32x2 gp;
                    gp.x = pk2bf(fmaxf(acc3[mt][0][r], 0.0f),
                                 fmaxf(acc3[mt][1][r], 0.0f));
                    gp.y = pk2bf(fmaxf(acc3[mt][2][r], 0.0f),
                                 fmaxf(acc3[mt][3][r], 0.0f));
                    *(u32x2*)(myE + XB(m, 8 * nfr)) = gp;
                }
        }
        // --- read g fragments now; V2 MFMAs deferred to next iteration ---
        #pragma unroll
        for (int mt = 0; mt < 2; mt++)
            #pragma unroll
            for (int kt = 0; kt < 2; kt++)
                agg[mt][kt] = *(const short8*)(myE + XB(nfr + 16 * mt, cbq + kt * 64));
    }
    v2_block(3);   // tail

    // ---- final: deferred exp/sigmoid + scan + weighted reduce (per wave) ----
    const float om0 = __expf(sOm[wave * 128 + 2 * lane]);
    const float om1 = __expf(sOm[wave * 128 + 2 * lane + 1]);
    const float al0 = 1.0f - om0;
    const float al1 = 1.0f - om1;

    float inc = om0 * om1;
    #pragma unroll
    for (int off = 1; off < 64; off <<= 1) {
        const float q = __shfl_up(inc, off, 64);
        if (lane >= off) inc *= q;
    }
    float Texc = __shfl_up(inc, 1, 64);
    if (lane == 0) Texc = 1.0f;

    const float T0 = Texc;
    const float T1 = Texc * om0;
    const float a0 = (T0 > 1e-4f) ? 1.0f : 0.0f;
    const float a1 = (T1 > 1e-4f) ? 1.0f : 0.0f;
    const float w0 = T0 * al0 * a0;
    const float w1 = T1 * al1 * a1;

    float cr = w0 * sigm(bf2f(sRgb[wave * 384 + (2 * lane) * 3 + 0])) +
               w1 * sigm(bf2f(sRgb[wave * 384 + (2 * lane + 1) * 3 + 0]));
    float cg = w0 * sigm(bf2f(sRgb[wave * 384 + (2 * lane) * 3 + 1])) +
               w1 * sigm(bf2f(sRgb[wave * 384 + (2 * lane + 1) * 3 + 1]));
    float cb = w0 * sigm(bf2f(sRgb[wave * 384 + (2 * lane) * 3 + 2])) +
               w1 * sigm(bf2f(sRgb[wave * 384 + (2 * lane + 1) * 3 + 2]));
    float tp = (a0 > 0.0f ? om0 : 1.0f) * (a1 > 0.0f ? om1 : 1.0f);

    #pragma unroll
    for (int off = 32; off > 0; off >>= 1) {
        cr += __shfl_xor(cr, off, 64);
        cg += __shfl_xor(cg, off, 64);
        cb += __shfl_xor(cb, off, 64);
        tp *= __shfl_xor(tp, off, 64);
    }

    if (lane == 0) {
        out[ray * 3 + 0] = cr;
        out[ray * 3 + 1] = cg;
        out[ray * 3 + 2] = cb;
        out[NRAYS * 3 + ray] = tp;
    }
}

extern "C" void kernel_launch(void* const* d_in, const int* in_sizes, int n_in,
                              void* d_out, int out_size, void* d_ws, size_t ws_size,
                              hipStream_t stream) {
    const float* orig = (const float*)d_in[0];
    const float* dirs = (const float*)d_in[1];
    const float* tmin = (const float*)d_in[2];
    const float* tmax = (const float*)d_in[3];
    const float* W1   = (const float*)d_in[4];
    const float* b1   = (const float*)d_in[5];
    const float* W2   = (const float*)d_in[6];
    const float* b2   = (const float*)d_in[7];
    const float* V1   = (const float*)d_in[8];
    const float* c1   = (const float*)d_in[9];
    const float* V2   = (const float*)d_in[10];
    const float* c2   = (const float*)d_in[11];

    short* img = (short*)d_ws;
    float* gvc = (float*)((char*)d_ws + GVC_OFF);

    prep_kernel<<<35, 256, 0, stream>>>(W1, b1, W2, b2, V1, c1, V2,
                                        tmin, tmax, img, gvc);
    march_kernel<<<NRAYS / 4, 256, 0, stream>>>(orig, dirs, tmin, tmax,
                                                b2, c2, V1, img, gvc,
                                                (float*)d_out);
}